// Round 9
// baseline (314.184 us; speedup 1.0000x reference)
//
#include <hip/hip_runtime.h>
#include <hip/hip_bf16.h>

#define NN 100000
#define NE 1600000
#define INF 256
#define OUTF 128
#define NB ((NN + 255) / 256)            // 391 node blocks
#define NBK ((NN + 127) / 128)           // 782 buckets of 128 nodes
#define CHUNK 4096
#define NBA ((NE + CHUNK - 1) / CHUNK)   // 391 chunks
#define NGRP (NN / 32)                   // 3125 (exact)

typedef __attribute__((ext_vector_type(8))) short short8;
typedef __attribute__((ext_vector_type(4))) float f32x4;

static __device__ __forceinline__ short f2bf(float f) {
    __hip_bfloat16 h = __float2bfloat16(f);
    return *reinterpret_cast<short*>(&h);
}

// ---------------------------------------------------------------------------
// Setup: block 0: wsv = W@a_src, wdv = W@a_dst, zero deg-histogram;
// blocks 1..8: swizzled bf16 B fragments of W_em.
// ---------------------------------------------------------------------------
__global__ void k_setup(const float* __restrict__ W, const float* __restrict__ a,
                        const float* __restrict__ Wem,
                        float* __restrict__ wsv, float* __restrict__ wdv,
                        ushort* __restrict__ Bsw, int* __restrict__ hist) {
    const int b = blockIdx.x, t = threadIdx.x;
    if (b == 0) {
        #pragma unroll
        for (int i = 0; i < 4; ++i) hist[i * 256 + t] = 0;
        const float* Wr = W + (size_t)t * OUTF;
        float sa = 0.f, sb = 0.f;
        #pragma unroll 8
        for (int k = 0; k < OUTF; ++k) {
            float w = Wr[k];
            sa += w * a[k];
            sb += w * a[OUTF + k];
        }
        wsv[t] = sa;
        wdv[t] = sb;
    } else {
        const int kt = b - 1;
        for (int idx = t; idx < 4096; idx += 256) {
            const int ct = idx >> 9;
            const int lane = (idx >> 3) & 63;
            const int j = idx & 7;
            const int k = kt * 32 + (lane >> 4) * 8 + j;
            const int c = ct * 16 + (lane & 15);
            Bsw[((size_t)(kt * 8 + ct) * 64 + lane) * 8 + j] =
                (ushort)f2bf(Wem[(size_t)k * OUTF + c]);
        }
    }
}

// ---------------------------------------------------------------------------
// MFMA matmul: hem(bf16) = x @ W_em; fused f32 s1 = x.ws, s2 = x.wd.
// hem SLICE-MAJOR: 8 slices of 16 features,
//   hem[((size_t)ct*NN + row)*16 + c16], slice = contiguous 3.2 MB.
// ---------------------------------------------------------------------------
__global__ __launch_bounds__(256) void k_mm(
    const float* __restrict__ x, const ushort* __restrict__ Bsw,
    const float* __restrict__ wsv, const float* __restrict__ wdv,
    float* __restrict__ s1, float* __restrict__ s2, ushort* __restrict__ hem) {
    const int t = threadIdx.x;
    const int w = t >> 6, lane = t & 63;
    const int br = blockIdx.x * 64 + w * 16;
    const int r0 = lane & 15, kq = lane >> 4;
    const int row = br + r0;
    const int rowc = (row < NN) ? row : NN - 1;
    const float* xp = x + (size_t)rowc * INF + kq * 8;
    const short8* bp = reinterpret_cast<const short8*>(Bsw);

    f32x4 acc[8];
    #pragma unroll
    for (int ct = 0; ct < 8; ++ct) acc[ct] = (f32x4){0.f, 0.f, 0.f, 0.f};
    float sa = 0.f, sb = 0.f;

    #pragma unroll
    for (int kt = 0; kt < 8; ++kt) {
        const float4 a0 = *reinterpret_cast<const float4*>(xp + kt * 32);
        const float4 a1 = *reinterpret_cast<const float4*>(xp + kt * 32 + 4);
        const float4 w0 = *reinterpret_cast<const float4*>(wsv + kt * 32 + kq * 8);
        const float4 w1 = *reinterpret_cast<const float4*>(wsv + kt * 32 + kq * 8 + 4);
        const float4 u0 = *reinterpret_cast<const float4*>(wdv + kt * 32 + kq * 8);
        const float4 u1 = *reinterpret_cast<const float4*>(wdv + kt * 32 + kq * 8 + 4);
        sa += a0.x * w0.x + a0.y * w0.y + a0.z * w0.z + a0.w * w0.w
            + a1.x * w1.x + a1.y * w1.y + a1.z * w1.z + a1.w * w1.w;
        sb += a0.x * u0.x + a0.y * u0.y + a0.z * u0.z + a0.w * u0.w
            + a1.x * u1.x + a1.y * u1.y + a1.z * u1.z + a1.w * u1.w;
        short8 af;
        af[0] = f2bf(a0.x); af[1] = f2bf(a0.y); af[2] = f2bf(a0.z); af[3] = f2bf(a0.w);
        af[4] = f2bf(a1.x); af[5] = f2bf(a1.y); af[6] = f2bf(a1.z); af[7] = f2bf(a1.w);
        #pragma unroll
        for (int ct = 0; ct < 8; ++ct) {
            const short8 bf = bp[(size_t)(kt * 8 + ct) * 64 + lane];
            acc[ct] = __builtin_amdgcn_mfma_f32_16x16x32_bf16(af, bf, acc[ct], 0, 0, 0);
        }
    }

    sa += __shfl_xor(sa, 16); sa += __shfl_xor(sa, 32);
    sb += __shfl_xor(sb, 16); sb += __shfl_xor(sb, 32);
    if (kq == 0 && row < NN) { s1[row] = sa; s2[row] = sb; }

    #pragma unroll
    for (int ct = 0; ct < 8; ++ct) {
        #pragma unroll
        for (int i = 0; i < 4; ++i) {
            const int rr = br + kq * 4 + i;
            if (rr < NN)
                hem[((size_t)ct * NN + rr) * 16 + r0] = (ushort)f2bf(acc[ct][i]);
        }
    }
}

// ---------------------------------------------------------------------------
// Per-chunk per-bucket counts (LDS only, no global atomics).
// ---------------------------------------------------------------------------
__global__ __launch_bounds__(256) void k_cnt(
    const int* __restrict__ src, int* __restrict__ cntA) {
    __shared__ int cnt[NBK];
    const int t = threadIdx.x;
    const int c = blockIdx.x;
    const int e0 = c * CHUNK;
    for (int i = t; i < NBK; i += 256) cnt[i] = 0;
    __syncthreads();
    for (int i = t; i < CHUNK; i += 256) {
        const int e = e0 + i;
        if (e < NE) atomicAdd(&cnt[src[e] >> 7], 1);
    }
    __syncthreads();
    for (int i = t; i < NBK; i += 256) cntA[(size_t)c * NBK + i] = cnt[i];
}

// ---------------------------------------------------------------------------
// Per-bucket scan over chunks: baseA[c][b] = exclusive sum, bsumB[b] = total.
// ---------------------------------------------------------------------------
__global__ __launch_bounds__(512) void k_cscan(
    const int* __restrict__ cntA, int* __restrict__ baseA,
    int* __restrict__ bsumB) {
    __shared__ int sm[512];
    const int b = blockIdx.x;
    const int t = threadIdx.x;
    const int v = (t < NBA) ? cntA[(size_t)t * NBK + b] : 0;
    sm[t] = v;
    __syncthreads();
    for (int off = 1; off < 512; off <<= 1) {
        const int add = (t >= off) ? sm[t - off] : 0;
        __syncthreads();
        sm[t] += add;
        __syncthreads();
    }
    if (t < NBA) baseA[(size_t)t * NBK + b] = sm[t] - v;
    if (t == 511) bsumB[b] = sm[511];
}

// ---------------------------------------------------------------------------
// Bucket exclusive scan (1 block, 1024 threads, NBK=782) + sentinels.
// ---------------------------------------------------------------------------
__global__ __launch_bounds__(1024) void k_bbase(
    const int* __restrict__ bsumB, int* __restrict__ bbase,
    int* __restrict__ offs) {
    __shared__ int sm[1024];
    const int t = threadIdx.x;
    const int v = (t < NBK) ? bsumB[t] : 0;
    sm[t] = v;
    __syncthreads();
    for (int off = 1; off < 1024; off <<= 1) {
        const int add = (t >= off) ? sm[t - off] : 0;
        __syncthreads();
        sm[t] += add;
        __syncthreads();
    }
    if (t < NBK) bbase[t] = sm[t] - v;
    if (t == 0) { bbase[NBK] = NE; offs[NN] = NE; }
}

// ---------------------------------------------------------------------------
// Pass A (fused edge_e): single-pass deterministic scatter into bucket runs.
// ebA record: { (dst<<7) | (src&127), vq },  vq = round((exp(sig(ee))-1)*16384)
// ---------------------------------------------------------------------------
__global__ __launch_bounds__(256) void k_binA(
    const int* __restrict__ src, const int* __restrict__ dst,
    const float* __restrict__ s1, const float* __restrict__ s2,
    float* __restrict__ ee_out, const int* __restrict__ bbase,
    const int* __restrict__ baseA, int2* __restrict__ ebA) {
    __shared__ int base[NBK];
    __shared__ int cnt[NBK];
    const int t = threadIdx.x;
    const int c = blockIdx.x;
    const int e0 = c * CHUNK;
    for (int i = t; i < NBK; i += 256) {
        base[i] = bbase[i] + baseA[(size_t)c * NBK + i];
        cnt[i] = 0;
    }
    __syncthreads();
    for (int i = t; i < CHUNK; i += 256) {
        const int e = e0 + i;
        if (e < NE) {
            const int s = src[e], d = dst[e];
            const float ee = s1[s] + s2[d];
            ee_out[e] = ee;
            const float ob = 1.f / (1.f + __expf(-ee));
            const float v = __expf(ob);                   // in (1, e)
            int vq = (int)((v - 1.f) * 16384.f + 0.5f);   // <= 28147
            vq = (vq > 32767) ? 32767 : vq;
            const int bk = s >> 7;
            const int r = atomicAdd(&cnt[bk], 1);
            ebA[base[bk] + r] = make_int2((d << 7) | (s & 127), vq);
        }
    }
}

// ---------------------------------------------------------------------------
// Pass B: one block per bucket. Pass 1: LDS per-node count + vq-sum over the
// contiguous bucket run, 128-scan -> per-node CSR offsets (written to offs[])
// and folded 1/denominator. Pass 2: scatter 4-byte records (dst<<15)|attq,
//   attq = round((16384+vq) * 32767 / (16384*cnt + vqsum))  (exact ints)
// ---------------------------------------------------------------------------
__global__ __launch_bounds__(256) void k_sortB(
    const int* __restrict__ bbase, const int2* __restrict__ ebA,
    uint* __restrict__ ebB, int* __restrict__ offs) {
    __shared__ int cnt[128];
    __shared__ int sum[128];
    __shared__ int sm[128];
    __shared__ int cur[128];
    __shared__ float fsl[128];
    const int b = blockIdx.x, t = threadIdx.x;
    const int n0 = b << 7;
    const int lo = bbase[b];
    const int hi = bbase[b + 1];
    if (t < 128) { cnt[t] = 0; sum[t] = 0; }
    __syncthreads();
    for (int i = lo + t; i < hi; i += 256) {
        const int2 r = ebA[i];
        const int sidx = r.x & 127;
        atomicAdd(&cnt[sidx], 1);
        atomicAdd(&sum[sidx], r.y);
    }
    __syncthreads();
    const int v = (t < 128) ? cnt[t] : 0;
    if (t < 128) sm[t] = v;
    __syncthreads();
    for (int off = 1; off < 128; off <<= 1) {
        int add = 0;
        if (t < 128 && t >= off) add = sm[t - off];
        __syncthreads();
        if (t < 128) sm[t] += add;
        __syncthreads();
    }
    if (t < 128) {
        const int excl = sm[t] - v;
        cur[t] = excl;
        const int node = n0 + t;
        if (node < NN) offs[node] = lo + excl;
        fsl[t] = (v > 0) ? 32767.f / (float)(v * 16384 + sum[t]) : 0.f;
    }
    __syncthreads();
    for (int i = lo + t; i < hi; i += 256) {
        const int2 r = ebA[i];
        const int sidx = r.x & 127;
        const uint d = ((unsigned)r.x) >> 7;
        const float att = (float)(16384 + r.y) * fsl[sidx];
        int attq = (int)(att + 0.5f);
        attq = (attq > 32767) ? 32767 : attq;
        const int p = atomicAdd(&cur[sidx], 1);
        ebB[lo + p] = (d << 15) | (uint)attq;
    }
}

// ---------------------------------------------------------------------------
// Degree counting sort (descending): bin = 1023 - min(deg,1023).
// k_deghist: LDS histogram -> global hist (few global atomics per block).
// ---------------------------------------------------------------------------
__global__ __launch_bounds__(256) void k_deghist(
    const int* __restrict__ offs, int* __restrict__ hist) {
    __shared__ int h[1024];
    const int t = threadIdx.x;
    for (int i = t; i < 1024; i += 256) h[i] = 0;
    __syncthreads();
    const int n = blockIdx.x * 256 + t;
    if (n < NN) {
        int d = offs[n + 1] - offs[n];
        d = (d > 1023) ? 1023 : d;
        atomicAdd(&h[1023 - d], 1);
    }
    __syncthreads();
    for (int i = t; i < 1024; i += 256)
        if (h[i]) atomicAdd(&hist[i], h[i]);
}

// Exclusive scan of the 1024-bin histogram -> running cursors dcur.
__global__ __launch_bounds__(1024) void k_degscan(
    const int* __restrict__ hist, int* __restrict__ dcur) {
    __shared__ int sm[1024];
    const int t = threadIdx.x;
    const int v = hist[t];
    sm[t] = v;
    __syncthreads();
    for (int off = 1; off < 1024; off <<= 1) {
        const int add = (t >= off) ? sm[t - off] : 0;
        __syncthreads();
        sm[t] += add;
        __syncthreads();
    }
    dcur[t] = sm[t] - v;
}

// Scatter node ids into perm, grouped by degree (descending).
__global__ __launch_bounds__(256) void k_degscat(
    const int* __restrict__ offs, int* __restrict__ dcur,
    int* __restrict__ perm) {
    __shared__ int lc[1024];
    __shared__ int lb[1024];
    const int t = threadIdx.x;
    for (int i = t; i < 1024; i += 256) lc[i] = 0;
    __syncthreads();
    const int n = blockIdx.x * 256 + t;
    int bin = -1;
    if (n < NN) {
        int d = offs[n + 1] - offs[n];
        d = (d > 1023) ? 1023 : d;
        bin = 1023 - d;
        atomicAdd(&lc[bin], 1);
    }
    __syncthreads();
    for (int i = t; i < 1024; i += 256) {
        const int c = lc[i];
        if (c) lb[i] = atomicAdd(&dcur[i], c);
    }
    __syncthreads();
    for (int i = t; i < 1024; i += 256) lc[i] = 0;
    __syncthreads();
    if (n < NN) {
        const int r = atomicAdd(&lc[bin], 1);
        perm[lb[bin] + r] = n;
    }
}

// ---------------------------------------------------------------------------
// Aggregation: R1/R8 structure + DEGREE-UNIFORM WAVES + nt record loads.
// slice = blockIdx&7 -> XCD-pinned 3.2 MB hem slice; grid 8*3125 blocks.
// Wave = 8 node-slots x 8 feature-pair lanes; node = perm[slot] so all 8
// nodes in a wave have (near-)equal degree -> no exec-mask divergence waste.
// nt record loads keep the 6.4 MB ebB stream from evicting the hem slice
// out of the XCD's 4 MB L2 (R8: 55 MB of thrash re-fetch).
// ---------------------------------------------------------------------------
__global__ __launch_bounds__(256) void k_aggregate(
    const uint* __restrict__ eb, const int* __restrict__ offs,
    const int* __restrict__ perm, const ushort* __restrict__ hem,
    float* __restrict__ out0) {
    const int slice = blockIdx.x & 7;
    const int grp = blockIdx.x >> 3;
    const int t = threadIdx.x;
    const int slot = grp * 32 + (t >> 3);    // NN = 32*NGRP exactly
    const int f = t & 7;                     // feature-pair within slice
    const int node = perm[slot];
    const char* hb = reinterpret_cast<const char*>(hem)
                   + (size_t)slice * NN * 32 + f * 4;
    const int beg = offs[node];
    const int end = offs[node + 1];

    float a0 = 0.f, a1 = 0.f;
    int j = beg;
    for (; j + 4 <= end; j += 4) {
        const uint r0 = __builtin_nontemporal_load(eb + j);
        const uint r1 = __builtin_nontemporal_load(eb + j + 1);
        const uint r2 = __builtin_nontemporal_load(eb + j + 2);
        const uint r3 = __builtin_nontemporal_load(eb + j + 3);
        const float w0 = (float)(r0 & 0x7fffu);
        const float w1 = (float)(r1 & 0x7fffu);
        const float w2 = (float)(r2 & 0x7fffu);
        const float w3 = (float)(r3 & 0x7fffu);
        const uint u0 = *reinterpret_cast<const uint*>(hb + ((r0 >> 15) << 5));
        const uint u1 = *reinterpret_cast<const uint*>(hb + ((r1 >> 15) << 5));
        const uint u2 = *reinterpret_cast<const uint*>(hb + ((r2 >> 15) << 5));
        const uint u3 = *reinterpret_cast<const uint*>(hb + ((r3 >> 15) << 5));
        a0 += w0 * __uint_as_float(u0 << 16) + w1 * __uint_as_float(u1 << 16)
            + w2 * __uint_as_float(u2 << 16) + w3 * __uint_as_float(u3 << 16);
        a1 += w0 * __uint_as_float(u0 & 0xffff0000u)
            + w1 * __uint_as_float(u1 & 0xffff0000u)
            + w2 * __uint_as_float(u2 & 0xffff0000u)
            + w3 * __uint_as_float(u3 & 0xffff0000u);
    }
    for (; j < end; ++j) {
        const uint r0 = __builtin_nontemporal_load(eb + j);
        const float w0 = (float)(r0 & 0x7fffu);
        const uint u0 = *reinterpret_cast<const uint*>(hb + ((r0 >> 15) << 5));
        a0 += w0 * __uint_as_float(u0 << 16);
        a1 += w0 * __uint_as_float(u0 & 0xffff0000u);
    }
    const float s = 1.f / 32767.f;
    float2 o;
    o.x = a0 * s;
    o.y = a1 * s;
    *reinterpret_cast<float2*>(out0 + (size_t)node * OUTF + slice * 16 + f * 2) = o;
}

// ---------------------------------------------------------------------------
extern "C" void kernel_launch(void* const* d_in, const int* in_sizes, int n_in,
                              void* d_out, int out_size, void* d_ws, size_t ws_size,
                              hipStream_t stream) {
    const float* x   = (const float*)d_in[0];
    const int* eidx  = (const int*)d_in[1];
    const float* W   = (const float*)d_in[2];
    const float* a   = (const float*)d_in[3];
    const float* Wem = (const float*)d_in[4];

    const int* src = eidx;
    const int* dst = eidx + NE;

    float* out0 = (float*)d_out;            // h_prime: NN*128
    float* out1 = out0 + (size_t)NN * OUTF; // edge_e: NE

    // workspace layout (~50 MB), 16B-aligned chunks
    float* wsv   = (float*)d_ws;                     // 256
    float* wdv   = wsv + 256;                        // 256
    float* s1    = wdv + 256;                        // NN
    float* s2    = s1 + NN;                          // NN
    ushort* hem  = (ushort*)(s2 + NN);               // NN*128 bf16 (slice-major)
    ushort* Bsw  = hem + (size_t)NN * OUTF;          // 32768
    int* offs    = (int*)(Bsw + 32768);              // NN+4 (sentinel + pad)
    int* bsumB   = offs + NN + 4;                    // NBK (pad to 784)
    int* bbase   = bsumB + 784;                      // NBK+1 (pad to 788)
    int* hist    = bbase + 788;                      // 1024
    int* dcur    = hist + 1024;                      // 1024
    int* perm    = dcur + 1024;                      // NN
    int* cntA    = perm + NN;                        // NBA*NBK
    int* baseA   = cntA + NBA * NBK;                 // NBA*NBK
    int2* ebA    = (int2*)(baseA + NBA * NBK);       // NE * 8B
    uint* ebB    = (uint*)(ebA + NE);                // NE * 4B

    hipLaunchKernelGGL(k_setup, dim3(9), dim3(256), 0, stream,
                       W, a, Wem, wsv, wdv, Bsw, hist);
    hipLaunchKernelGGL(k_mm, dim3((NN + 63) / 64), dim3(256), 0, stream,
                       x, Bsw, wsv, wdv, s1, s2, hem);
    hipLaunchKernelGGL(k_cnt, dim3(NBA), dim3(256), 0, stream, src, cntA);
    hipLaunchKernelGGL(k_cscan, dim3(NBK), dim3(512), 0, stream, cntA, baseA, bsumB);
    hipLaunchKernelGGL(k_bbase, dim3(1), dim3(1024), 0, stream, bsumB, bbase, offs);
    hipLaunchKernelGGL(k_binA, dim3(NBA), dim3(256), 0, stream,
                       src, dst, s1, s2, out1, bbase, baseA, ebA);
    hipLaunchKernelGGL(k_sortB, dim3(NBK), dim3(256), 0, stream,
                       bbase, ebA, ebB, offs);
    hipLaunchKernelGGL(k_deghist, dim3(NB), dim3(256), 0, stream, offs, hist);
    hipLaunchKernelGGL(k_degscan, dim3(1), dim3(1024), 0, stream, hist, dcur);
    hipLaunchKernelGGL(k_degscat, dim3(NB), dim3(256), 0, stream, offs, dcur, perm);
    hipLaunchKernelGGL(k_aggregate, dim3(8 * NGRP), dim3(256), 0, stream,
                       ebB, offs, perm, hem, out0);
}

// Round 10
// 233.114 us; speedup vs baseline: 1.3478x; 1.3478x over previous
//
#include <hip/hip_runtime.h>
#include <hip/hip_bf16.h>

#define NN 100000
#define NE 1600000
#define INF 256
#define OUTF 128
#define NHALF 50000
#define NBK ((NN + 127) / 128)           // 782 buckets of 128 nodes
#define CHUNK 4096
#define NBA ((NE + CHUNK - 1) / CHUNK)   // 391 chunks

typedef __attribute__((ext_vector_type(8))) short short8;
typedef __attribute__((ext_vector_type(4))) float f32x4;

static __device__ __forceinline__ short f2bf(float f) {
    __hip_bfloat16 h = __float2bfloat16(f);
    return *reinterpret_cast<short*>(&h);
}

// ---------------------------------------------------------------------------
// Setup: block 0: wsv = W@a_src, wdv = W@a_dst;
// blocks 1..8: swizzled bf16 B fragments of W_em.
// ---------------------------------------------------------------------------
__global__ void k_setup(const float* __restrict__ W, const float* __restrict__ a,
                        const float* __restrict__ Wem,
                        float* __restrict__ wsv, float* __restrict__ wdv,
                        ushort* __restrict__ Bsw) {
    const int b = blockIdx.x, t = threadIdx.x;
    if (b == 0) {
        const float* Wr = W + (size_t)t * OUTF;
        float sa = 0.f, sb = 0.f;
        #pragma unroll 8
        for (int k = 0; k < OUTF; ++k) {
            float w = Wr[k];
            sa += w * a[k];
            sb += w * a[OUTF + k];
        }
        wsv[t] = sa;
        wdv[t] = sb;
    } else {
        const int kt = b - 1;
        for (int idx = t; idx < 4096; idx += 256) {
            const int ct = idx >> 9;
            const int lane = (idx >> 3) & 63;
            const int j = idx & 7;
            const int k = kt * 32 + (lane >> 4) * 8 + j;
            const int c = ct * 16 + (lane & 15);
            Bsw[((size_t)(kt * 8 + ct) * 64 + lane) * 8 + j] =
                (ushort)f2bf(Wem[(size_t)k * OUTF + c]);
        }
    }
}

// ---------------------------------------------------------------------------
// MFMA matmul: hem(bf16) = x @ W_em; fused f32 s1 = x.ws, s2 = x.wd.
// hem stored as 8 XCD-L2-resident TILES of 64-byte rows (R6 layout, proven):
//   tile (fs 0..3, dh 0..1): [(fs*2+dh)*NHALF + (row - dh*NHALF)]*32 + cw
//   (features fs*32..+31 for rows in half dh; tile = 3.2 MB)
// ---------------------------------------------------------------------------
__global__ __launch_bounds__(256) void k_mm(
    const float* __restrict__ x, const ushort* __restrict__ Bsw,
    const float* __restrict__ wsv, const float* __restrict__ wdv,
    float* __restrict__ s1, float* __restrict__ s2, ushort* __restrict__ hem) {
    const int t = threadIdx.x;
    const int w = t >> 6, lane = t & 63;
    const int br = blockIdx.x * 64 + w * 16;
    const int r0 = lane & 15, kq = lane >> 4;
    const int row = br + r0;
    const int rowc = (row < NN) ? row : NN - 1;
    const float* xp = x + (size_t)rowc * INF + kq * 8;
    const short8* bp = reinterpret_cast<const short8*>(Bsw);

    f32x4 acc[8];
    #pragma unroll
    for (int ct = 0; ct < 8; ++ct) acc[ct] = (f32x4){0.f, 0.f, 0.f, 0.f};
    float sa = 0.f, sb = 0.f;

    #pragma unroll
    for (int kt = 0; kt < 8; ++kt) {
        const float4 a0 = *reinterpret_cast<const float4*>(xp + kt * 32);
        const float4 a1 = *reinterpret_cast<const float4*>(xp + kt * 32 + 4);
        const float4 w0 = *reinterpret_cast<const float4*>(wsv + kt * 32 + kq * 8);
        const float4 w1 = *reinterpret_cast<const float4*>(wsv + kt * 32 + kq * 8 + 4);
        const float4 u0 = *reinterpret_cast<const float4*>(wdv + kt * 32 + kq * 8);
        const float4 u1 = *reinterpret_cast<const float4*>(wdv + kt * 32 + kq * 8 + 4);
        sa += a0.x * w0.x + a0.y * w0.y + a0.z * w0.z + a0.w * w0.w
            + a1.x * w1.x + a1.y * w1.y + a1.z * w1.z + a1.w * w1.w;
        sb += a0.x * u0.x + a0.y * u0.y + a0.z * u0.z + a0.w * u0.w
            + a1.x * u1.x + a1.y * u1.y + a1.z * u1.z + a1.w * u1.w;
        short8 af;
        af[0] = f2bf(a0.x); af[1] = f2bf(a0.y); af[2] = f2bf(a0.z); af[3] = f2bf(a0.w);
        af[4] = f2bf(a1.x); af[5] = f2bf(a1.y); af[6] = f2bf(a1.z); af[7] = f2bf(a1.w);
        #pragma unroll
        for (int ct = 0; ct < 8; ++ct) {
            const short8 bf = bp[(size_t)(kt * 8 + ct) * 64 + lane];
            acc[ct] = __builtin_amdgcn_mfma_f32_16x16x32_bf16(af, bf, acc[ct], 0, 0, 0);
        }
    }

    sa += __shfl_xor(sa, 16); sa += __shfl_xor(sa, 32);
    sb += __shfl_xor(sb, 16); sb += __shfl_xor(sb, 32);
    if (kq == 0 && row < NN) { s1[row] = sa; s2[row] = sb; }

    #pragma unroll
    for (int ct = 0; ct < 8; ++ct) {
        const int fs = ct >> 1;
        const int cw = (ct & 1) * 16 + r0;
        #pragma unroll
        for (int i = 0; i < 4; ++i) {
            const int rr = br + kq * 4 + i;
            if (rr < NN) {
                const int dh = (rr >= NHALF) ? 1 : 0;
                const int np = rr - dh * NHALF;
                hem[((size_t)(fs * 2 + dh) * NHALF + np) * 32 + cw] =
                    (ushort)f2bf(acc[ct][i]);
            }
        }
    }
}

// ---------------------------------------------------------------------------
// Per-chunk per-bucket counts (LDS only, no global atomics).
// ---------------------------------------------------------------------------
__global__ __launch_bounds__(256) void k_cnt(
    const int* __restrict__ src, int* __restrict__ cntA) {
    __shared__ int cnt[NBK];
    const int t = threadIdx.x;
    const int c = blockIdx.x;
    const int e0 = c * CHUNK;
    for (int i = t; i < NBK; i += 256) cnt[i] = 0;
    __syncthreads();
    for (int i = t; i < CHUNK; i += 256) {
        const int e = e0 + i;
        if (e < NE) atomicAdd(&cnt[src[e] >> 7], 1);
    }
    __syncthreads();
    for (int i = t; i < NBK; i += 256) cntA[(size_t)c * NBK + i] = cnt[i];
}

// ---------------------------------------------------------------------------
// Per-bucket scan over chunks: baseA[c][b] = exclusive sum, bsumB[b] = total.
// ---------------------------------------------------------------------------
__global__ __launch_bounds__(512) void k_cscan(
    const int* __restrict__ cntA, int* __restrict__ baseA,
    int* __restrict__ bsumB) {
    __shared__ int sm[512];
    const int b = blockIdx.x;
    const int t = threadIdx.x;
    const int v = (t < NBA) ? cntA[(size_t)t * NBK + b] : 0;
    sm[t] = v;
    __syncthreads();
    for (int off = 1; off < 512; off <<= 1) {
        const int add = (t >= off) ? sm[t - off] : 0;
        __syncthreads();
        sm[t] += add;
        __syncthreads();
    }
    if (t < NBA) baseA[(size_t)t * NBK + b] = sm[t] - v;
    if (t == 511) bsumB[b] = sm[511];
}

// ---------------------------------------------------------------------------
// Bucket exclusive scan (1 block, 1024 threads, NBK=782) + sentinels.
// ---------------------------------------------------------------------------
__global__ __launch_bounds__(1024) void k_bbase(
    const int* __restrict__ bsumB, int* __restrict__ bbase,
    int* __restrict__ offs2) {
    __shared__ int sm[1024];
    const int t = threadIdx.x;
    const int v = (t < NBK) ? bsumB[t] : 0;
    sm[t] = v;
    __syncthreads();
    for (int off = 1; off < 1024; off <<= 1) {
        const int add = (t >= off) ? sm[t - off] : 0;
        __syncthreads();
        sm[t] += add;
        __syncthreads();
    }
    if (t < NBK) bbase[t] = sm[t] - v;
    if (t == 0) { bbase[NBK] = NE; offs2[2 * NN] = NE; }
}

// ---------------------------------------------------------------------------
// Pass A (fused edge_e): single-pass deterministic scatter into bucket runs.
// ebA record: { (dst<<7) | (src&127), vq },  vq = round((exp(sig(ee))-1)*16384)
// ---------------------------------------------------------------------------
__global__ __launch_bounds__(256) void k_binA(
    const int* __restrict__ src, const int* __restrict__ dst,
    const float* __restrict__ s1, const float* __restrict__ s2,
    float* __restrict__ ee_out, const int* __restrict__ bbase,
    const int* __restrict__ baseA, int2* __restrict__ ebA) {
    __shared__ int base[NBK];
    __shared__ int cnt[NBK];
    const int t = threadIdx.x;
    const int c = blockIdx.x;
    const int e0 = c * CHUNK;
    for (int i = t; i < NBK; i += 256) {
        base[i] = bbase[i] + baseA[(size_t)c * NBK + i];
        cnt[i] = 0;
    }
    __syncthreads();
    for (int i = t; i < CHUNK; i += 256) {
        const int e = e0 + i;
        if (e < NE) {
            const int s = src[e], d = dst[e];
            const float ee = s1[s] + s2[d];
            ee_out[e] = ee;
            const float ob = 1.f / (1.f + __expf(-ee));
            const float v = __expf(ob);                   // in (1, e)
            int vq = (int)((v - 1.f) * 16384.f + 0.5f);   // <= 28147
            vq = (vq > 32767) ? 32767 : vq;
            const int bk = s >> 7;
            const int r = atomicAdd(&cnt[bk], 1);
            ebA[base[bk] + r] = make_int2((d << 7) | (s & 127), vq);
        }
    }
}

// ---------------------------------------------------------------------------
// Pass B: one block per bucket. 256 virtual bins = (node-in-bucket, dst-half).
// CSR offs2[2n+dh]; record = (dp<<15) | attq, dp = dst - dh*50000.
//   attq = round((16384+vq) * 32767 / (16384*cnt + vqsum))  (exact ints)
// ---------------------------------------------------------------------------
__global__ __launch_bounds__(256) void k_sortB(
    const int* __restrict__ bbase, const int2* __restrict__ ebA,
    uint* __restrict__ ebB, int* __restrict__ offs2) {
    __shared__ int cnt[256];
    __shared__ int sum[128];
    __shared__ int sm[256];
    __shared__ int cur[256];
    __shared__ float fsl[128];
    const int b = blockIdx.x, t = threadIdx.x;
    const int n0 = b << 7;
    const int lo = bbase[b];
    const int hi = bbase[b + 1];
    cnt[t] = 0;
    if (t < 128) sum[t] = 0;
    __syncthreads();
    for (int i = lo + t; i < hi; i += 256) {
        const int2 r = ebA[i];
        const int sidx = r.x & 127;
        const uint d = ((unsigned)r.x) >> 7;
        const int vid = (sidx << 1) | (d >= (uint)NHALF ? 1 : 0);
        atomicAdd(&cnt[vid], 1);
        atomicAdd(&sum[sidx], r.y);
    }
    __syncthreads();
    const int v = cnt[t];
    sm[t] = v;
    __syncthreads();
    for (int off = 1; off < 256; off <<= 1) {
        const int add = (t >= off) ? sm[t - off] : 0;
        __syncthreads();
        sm[t] += add;
        __syncthreads();
    }
    const int excl = sm[t] - v;
    cur[t] = excl;
    if (n0 + (t >> 1) < NN) offs2[n0 * 2 + t] = lo + excl;
    if (t < 128) {
        const int c = cnt[2 * t] + cnt[2 * t + 1];
        fsl[t] = (c > 0) ? 32767.f / (float)(c * 16384 + sum[t]) : 0.f;
    }
    __syncthreads();
    for (int i = lo + t; i < hi; i += 256) {
        const int2 r = ebA[i];
        const int sidx = r.x & 127;
        const uint d = ((unsigned)r.x) >> 7;
        const int dh = (d >= (uint)NHALF) ? 1 : 0;
        const uint dp = d - (uint)(dh * NHALF);
        const float att = (float)(16384 + r.y) * fsl[sidx];
        int attq = (int)(att + 0.5f);
        attq = (attq > 32767) ? 32767 : attq;
        const int p = atomicAdd(&cur[(sidx << 1) | dh], 1);
        ebB[lo + p] = (dp << 15) | (uint)attq;
    }
}

// ---------------------------------------------------------------------------
// Aggregation v5: single pass, registers carry across the dh phases.
// Wave = 4 nodes x 16 lanes; lane owns ONE uint (2 features) of the 64 B row
// -> 16 lanes coalesce to exactly one line-touch per edge per fs
// (halves L2 granule traffic vs 32 B rows: 819 -> 410 GB, the R8 limiter).
// fs = blockIdx&3 -> XCD-stable (XCD = blockIdx&7, fs = XCD&3): each XCD
// gathers one 3.2 MB tile per phase; dh=0 edges first (tile fs,0) then dh=1
// (tile fs,1), acc in registers -> no tmp, no combine, single store.
// ---------------------------------------------------------------------------
__global__ __launch_bounds__(256) void k_aggregate(
    const uint* __restrict__ eb, const int* __restrict__ offs2,
    const ushort* __restrict__ hem, float* __restrict__ out0) {
    const int fs = blockIdx.x & 3;
    const int grp = blockIdx.x >> 2;           // 0..6249
    const int t = threadIdx.x;
    const int node = grp * 16 + (t >> 4);      // NN = 16*6250 exactly
    const int lane16 = t & 15;
    const uint* tile0 = reinterpret_cast<const uint*>(hem)
                      + (size_t)(fs * 2) * NHALF * 16 + lane16;
    const uint* tile1 = tile0 + (size_t)NHALF * 16;

    const int b0 = offs2[2 * node];
    const int b1 = offs2[2 * node + 1];
    const int b2 = offs2[2 * node + 2];

    float a0 = 0.f, a1 = 0.f;

    int j = b0;
    for (; j + 2 <= b1; j += 2) {
        const uint r0 = eb[j];
        const uint r1 = eb[j + 1];
        const float w0 = (float)(r0 & 0x7fffu);
        const float w1 = (float)(r1 & 0x7fffu);
        const uint u0 = tile0[(size_t)(r0 >> 15) * 16];
        const uint u1 = tile0[(size_t)(r1 >> 15) * 16];
        a0 += w0 * __uint_as_float(u0 << 16) + w1 * __uint_as_float(u1 << 16);
        a1 += w0 * __uint_as_float(u0 & 0xffff0000u)
            + w1 * __uint_as_float(u1 & 0xffff0000u);
    }
    if (j < b1) {
        const uint r0 = eb[j];
        const float w0 = (float)(r0 & 0x7fffu);
        const uint u0 = tile0[(size_t)(r0 >> 15) * 16];
        a0 += w0 * __uint_as_float(u0 << 16);
        a1 += w0 * __uint_as_float(u0 & 0xffff0000u);
    }
    j = b1;
    for (; j + 2 <= b2; j += 2) {
        const uint r0 = eb[j];
        const uint r1 = eb[j + 1];
        const float w0 = (float)(r0 & 0x7fffu);
        const float w1 = (float)(r1 & 0x7fffu);
        const uint u0 = tile1[(size_t)(r0 >> 15) * 16];
        const uint u1 = tile1[(size_t)(r1 >> 15) * 16];
        a0 += w0 * __uint_as_float(u0 << 16) + w1 * __uint_as_float(u1 << 16);
        a1 += w0 * __uint_as_float(u0 & 0xffff0000u)
            + w1 * __uint_as_float(u1 & 0xffff0000u);
    }
    if (j < b2) {
        const uint r0 = eb[j];
        const float w0 = (float)(r0 & 0x7fffu);
        const uint u0 = tile1[(size_t)(r0 >> 15) * 16];
        a0 += w0 * __uint_as_float(u0 << 16);
        a1 += w0 * __uint_as_float(u0 & 0xffff0000u);
    }

    const float s = 1.f / 32767.f;
    float2 o;
    o.x = a0 * s;
    o.y = a1 * s;
    *reinterpret_cast<float2*>(
        out0 + (size_t)node * OUTF + fs * 32 + lane16 * 2) = o;
}

// ---------------------------------------------------------------------------
extern "C" void kernel_launch(void* const* d_in, const int* in_sizes, int n_in,
                              void* d_out, int out_size, void* d_ws, size_t ws_size,
                              hipStream_t stream) {
    const float* x   = (const float*)d_in[0];
    const int* eidx  = (const int*)d_in[1];
    const float* W   = (const float*)d_in[2];
    const float* a   = (const float*)d_in[3];
    const float* Wem = (const float*)d_in[4];

    const int* src = eidx;
    const int* dst = eidx + NE;

    float* out0 = (float*)d_out;            // h_prime: NN*128
    float* out1 = out0 + (size_t)NN * OUTF; // edge_e: NE

    // workspace layout (~50 MB), 16B-aligned chunks
    float* wsv   = (float*)d_ws;                     // 256
    float* wdv   = wsv + 256;                        // 256
    float* s1    = wdv + 256;                        // NN
    float* s2    = s1 + NN;                          // NN
    ushort* hem  = (ushort*)(s2 + NN);               // NN*128 bf16 (tiled layout)
    ushort* Bsw  = hem + (size_t)NN * OUTF;          // 32768
    int* offs2   = (int*)(Bsw + 32768);              // 2*NN+4 (sentinel + pad)
    int* bsumB   = offs2 + 2 * NN + 4;               // NBK (pad to 784)
    int* bbase   = bsumB + 784;                      // NBK+1 (pad to 788)
    int* cntA    = bbase + 788;                      // NBA*NBK
    int* baseA   = cntA + NBA * NBK;                 // NBA*NBK
    int2* ebA    = (int2*)(baseA + NBA * NBK);       // NE * 8B
    uint* ebB    = (uint*)(ebA + NE);                // NE * 4B

    hipLaunchKernelGGL(k_setup, dim3(9), dim3(256), 0, stream,
                       W, a, Wem, wsv, wdv, Bsw);
    hipLaunchKernelGGL(k_mm, dim3((NN + 63) / 64), dim3(256), 0, stream,
                       x, Bsw, wsv, wdv, s1, s2, hem);
    hipLaunchKernelGGL(k_cnt, dim3(NBA), dim3(256), 0, stream, src, cntA);
    hipLaunchKernelGGL(k_cscan, dim3(NBK), dim3(512), 0, stream, cntA, baseA, bsumB);
    hipLaunchKernelGGL(k_bbase, dim3(1), dim3(1024), 0, stream, bsumB, bbase, offs2);
    hipLaunchKernelGGL(k_binA, dim3(NBA), dim3(256), 0, stream,
                       src, dst, s1, s2, out1, bbase, baseA, ebA);
    hipLaunchKernelGGL(k_sortB, dim3(NBK), dim3(256), 0, stream,
                       bbase, ebA, ebB, offs2);
    hipLaunchKernelGGL(k_aggregate, dim3(4 * (NN / 16)), dim3(256), 0, stream,
                       ebB, offs2, hem, out0);
}

// Round 11
// 190.947 us; speedup vs baseline: 1.6454x; 1.2208x over previous
//
#include <hip/hip_runtime.h>
#include <hip/hip_bf16.h>

#define NN 100000
#define NE 1600000
#define INF 256
#define OUTF 128
#define NBK ((NN + 127) / 128)           // 782 buckets of 128 nodes
#define CHUNK 4096
#define NBA ((NE + CHUNK - 1) / CHUNK)   // 391 chunks
#define NGRP (NN / 32)                   // 3125 (exact)
#define SCAP 6144                        // sortB LDS record cap (bucket ~Poisson(2048))

typedef __attribute__((ext_vector_type(8))) short short8;
typedef __attribute__((ext_vector_type(4))) float f32x4;

static __device__ __forceinline__ short f2bf(float f) {
    __hip_bfloat16 h = __float2bfloat16(f);
    return *reinterpret_cast<short*>(&h);
}

// ---------------------------------------------------------------------------
// Setup (fused): block 0: wsv = W@a_src, wdv = W@a_dst;
// blocks 1..8: swizzled bf16 B fragments of W_em;
// blocks 9..9+NBA-1: per-chunk per-bucket edge counts (concurrent with above).
// ---------------------------------------------------------------------------
__global__ void k_setup(const float* __restrict__ W, const float* __restrict__ a,
                        const float* __restrict__ Wem, const int* __restrict__ src,
                        float* __restrict__ wsv, float* __restrict__ wdv,
                        ushort* __restrict__ Bsw, int* __restrict__ cntA) {
    const int b = blockIdx.x, t = threadIdx.x;
    if (b == 0) {
        const float* Wr = W + (size_t)t * OUTF;
        float sa = 0.f, sb = 0.f;
        #pragma unroll 8
        for (int k = 0; k < OUTF; ++k) {
            float w = Wr[k];
            sa += w * a[k];
            sb += w * a[OUTF + k];
        }
        wsv[t] = sa;
        wdv[t] = sb;
    } else if (b <= 8) {
        const int kt = b - 1;
        for (int idx = t; idx < 4096; idx += 256) {
            const int ct = idx >> 9;
            const int lane = (idx >> 3) & 63;
            const int j = idx & 7;
            const int k = kt * 32 + (lane >> 4) * 8 + j;
            const int c = ct * 16 + (lane & 15);
            Bsw[((size_t)(kt * 8 + ct) * 64 + lane) * 8 + j] =
                (ushort)f2bf(Wem[(size_t)k * OUTF + c]);
        }
    } else {
        __shared__ int cnt[NBK];
        const int c = b - 9;
        const int e0 = c * CHUNK;
        for (int i = t; i < NBK; i += 256) cnt[i] = 0;
        __syncthreads();
        for (int i = t; i < CHUNK; i += 256) {
            const int e = e0 + i;
            if (e < NE) atomicAdd(&cnt[src[e] >> 7], 1);
        }
        __syncthreads();
        for (int i = t; i < NBK; i += 256) cntA[(size_t)c * NBK + i] = cnt[i];
    }
}

// ---------------------------------------------------------------------------
// MFMA matmul: hem(bf16) = x @ W_em; fused f32 s1 = x.ws, s2 = x.wd.
// hem SLICE-MAJOR (R8 layout, proven): 8 slices of 16 features,
//   hem[((size_t)ct*NN + row)*16 + c16], slice = contiguous 3.2 MB.
// ---------------------------------------------------------------------------
__global__ __launch_bounds__(256) void k_mm(
    const float* __restrict__ x, const ushort* __restrict__ Bsw,
    const float* __restrict__ wsv, const float* __restrict__ wdv,
    float* __restrict__ s1, float* __restrict__ s2, ushort* __restrict__ hem) {
    const int t = threadIdx.x;
    const int w = t >> 6, lane = t & 63;
    const int br = blockIdx.x * 64 + w * 16;
    const int r0 = lane & 15, kq = lane >> 4;
    const int row = br + r0;
    const int rowc = (row < NN) ? row : NN - 1;
    const float* xp = x + (size_t)rowc * INF + kq * 8;
    const short8* bp = reinterpret_cast<const short8*>(Bsw);

    f32x4 acc[8];
    #pragma unroll
    for (int ct = 0; ct < 8; ++ct) acc[ct] = (f32x4){0.f, 0.f, 0.f, 0.f};
    float sa = 0.f, sb = 0.f;

    #pragma unroll
    for (int kt = 0; kt < 8; ++kt) {
        const float4 a0 = *reinterpret_cast<const float4*>(xp + kt * 32);
        const float4 a1 = *reinterpret_cast<const float4*>(xp + kt * 32 + 4);
        const float4 w0 = *reinterpret_cast<const float4*>(wsv + kt * 32 + kq * 8);
        const float4 w1 = *reinterpret_cast<const float4*>(wsv + kt * 32 + kq * 8 + 4);
        const float4 u0 = *reinterpret_cast<const float4*>(wdv + kt * 32 + kq * 8);
        const float4 u1 = *reinterpret_cast<const float4*>(wdv + kt * 32 + kq * 8 + 4);
        sa += a0.x * w0.x + a0.y * w0.y + a0.z * w0.z + a0.w * w0.w
            + a1.x * w1.x + a1.y * w1.y + a1.z * w1.z + a1.w * w1.w;
        sb += a0.x * u0.x + a0.y * u0.y + a0.z * u0.z + a0.w * u0.w
            + a1.x * u1.x + a1.y * u1.y + a1.z * u1.z + a1.w * u1.w;
        short8 af;
        af[0] = f2bf(a0.x); af[1] = f2bf(a0.y); af[2] = f2bf(a0.z); af[3] = f2bf(a0.w);
        af[4] = f2bf(a1.x); af[5] = f2bf(a1.y); af[6] = f2bf(a1.z); af[7] = f2bf(a1.w);
        #pragma unroll
        for (int ct = 0; ct < 8; ++ct) {
            const short8 bf = bp[(size_t)(kt * 8 + ct) * 64 + lane];
            acc[ct] = __builtin_amdgcn_mfma_f32_16x16x32_bf16(af, bf, acc[ct], 0, 0, 0);
        }
    }

    sa += __shfl_xor(sa, 16); sa += __shfl_xor(sa, 32);
    sb += __shfl_xor(sb, 16); sb += __shfl_xor(sb, 32);
    if (kq == 0 && row < NN) { s1[row] = sa; s2[row] = sb; }

    #pragma unroll
    for (int ct = 0; ct < 8; ++ct) {
        #pragma unroll
        for (int i = 0; i < 4; ++i) {
            const int rr = br + kq * 4 + i;
            if (rr < NN)
                hem[((size_t)ct * NN + rr) * 16 + r0] = (ushort)f2bf(acc[ct][i]);
        }
    }
}

// ---------------------------------------------------------------------------
// Per-bucket scan over chunks: baseA[c][b] = exclusive sum, bsumB[b] = total.
// ---------------------------------------------------------------------------
__global__ __launch_bounds__(512) void k_cscan(
    const int* __restrict__ cntA, int* __restrict__ baseA,
    int* __restrict__ bsumB) {
    __shared__ int sm[512];
    const int b = blockIdx.x;
    const int t = threadIdx.x;
    const int v = (t < NBA) ? cntA[(size_t)t * NBK + b] : 0;
    sm[t] = v;
    __syncthreads();
    for (int off = 1; off < 512; off <<= 1) {
        const int add = (t >= off) ? sm[t - off] : 0;
        __syncthreads();
        sm[t] += add;
        __syncthreads();
    }
    if (t < NBA) baseA[(size_t)t * NBK + b] = sm[t] - v;
    if (t == 511) bsumB[b] = sm[511];
}

// ---------------------------------------------------------------------------
// Bucket exclusive scan (1 block, 1024 threads, NBK=782) + sentinels.
// ---------------------------------------------------------------------------
__global__ __launch_bounds__(1024) void k_bbase(
    const int* __restrict__ bsumB, int* __restrict__ bbase,
    int* __restrict__ offs) {
    __shared__ int sm[1024];
    const int t = threadIdx.x;
    const int v = (t < NBK) ? bsumB[t] : 0;
    sm[t] = v;
    __syncthreads();
    for (int off = 1; off < 1024; off <<= 1) {
        const int add = (t >= off) ? sm[t - off] : 0;
        __syncthreads();
        sm[t] += add;
        __syncthreads();
    }
    if (t < NBK) bbase[t] = sm[t] - v;
    if (t == 0) { bbase[NBK] = NE; offs[NN] = NE; }
}

// ---------------------------------------------------------------------------
// Pass A (fused edge_e): single-pass deterministic scatter into bucket runs.
// ebA record: { (dst<<7) | (src&127), vq },  vq = round((exp(sig(ee))-1)*16384)
// ee_out stored nontemporal (pure output stream; keep L2 for gathers/scatter).
// ---------------------------------------------------------------------------
__global__ __launch_bounds__(256) void k_binA(
    const int* __restrict__ src, const int* __restrict__ dst,
    const float* __restrict__ s1, const float* __restrict__ s2,
    float* __restrict__ ee_out, const int* __restrict__ bbase,
    const int* __restrict__ baseA, int2* __restrict__ ebA) {
    __shared__ int base[NBK];
    __shared__ int cnt[NBK];
    const int t = threadIdx.x;
    const int c = blockIdx.x;
    const int e0 = c * CHUNK;
    for (int i = t; i < NBK; i += 256) {
        base[i] = bbase[i] + baseA[(size_t)c * NBK + i];
        cnt[i] = 0;
    }
    __syncthreads();
    for (int i = t; i < CHUNK; i += 256) {
        const int e = e0 + i;
        if (e < NE) {
            const int s = src[e], d = dst[e];
            const float ee = s1[s] + s2[d];
            __builtin_nontemporal_store(ee, ee_out + e);
            const float ob = 1.f / (1.f + __expf(-ee));
            const float v = __expf(ob);                   // in (1, e)
            int vq = (int)((v - 1.f) * 16384.f + 0.5f);   // <= 28147
            vq = (vq > 32767) ? 32767 : vq;
            const int bk = s >> 7;
            const int r = atomicAdd(&cnt[bk], 1);
            ebA[base[bk] + r] = make_int2((d << 7) | (s & 127), vq);
        }
    }
}

// ---------------------------------------------------------------------------
// Pass B: one block per bucket, SINGLE global read of the bucket run.
// Records staged in LDS (cap SCAP; bucket ~ Poisson(2048), SCAP = +90 sigma;
// overflow path re-reads global for correctness). Pass 1 counts + vq-sums
// while staging; 128-scan -> CSR offs + folded 1/denominator; pass 2
// scatters 4-byte records (dst<<15)|attq from LDS.
//   attq = round((16384+vq) * 32767 / (16384*cnt + vqsum))  (exact ints)
// ---------------------------------------------------------------------------
__global__ __launch_bounds__(256) void k_sortB(
    const int* __restrict__ bbase, const int2* __restrict__ ebA,
    uint* __restrict__ ebB, int* __restrict__ offs) {
    __shared__ uint rx[SCAP];
    __shared__ ushort ry[SCAP];
    __shared__ int cnt[128];
    __shared__ int sum[128];
    __shared__ int sm[128];
    __shared__ int cur[128];
    __shared__ float fsl[128];
    const int b = blockIdx.x, t = threadIdx.x;
    const int n0 = b << 7;
    const int lo = bbase[b];
    const int hi = bbase[b + 1];
    const int n = hi - lo;
    if (t < 128) { cnt[t] = 0; sum[t] = 0; }
    __syncthreads();
    for (int i = t; i < n; i += 256) {
        const int2 r = ebA[lo + i];
        if (i < SCAP) { rx[i] = (uint)r.x; ry[i] = (ushort)r.y; }
        const int sidx = r.x & 127;
        atomicAdd(&cnt[sidx], 1);
        atomicAdd(&sum[sidx], r.y);
    }
    __syncthreads();
    const int v = (t < 128) ? cnt[t] : 0;
    if (t < 128) sm[t] = v;
    __syncthreads();
    for (int off = 1; off < 128; off <<= 1) {
        int add = 0;
        if (t < 128 && t >= off) add = sm[t - off];
        __syncthreads();
        if (t < 128) sm[t] += add;
        __syncthreads();
    }
    if (t < 128) {
        const int excl = sm[t] - v;
        cur[t] = excl;
        const int node = n0 + t;
        if (node < NN) offs[node] = lo + excl;
        fsl[t] = (v > 0) ? 32767.f / (float)(v * 16384 + sum[t]) : 0.f;
    }
    __syncthreads();
    for (int i = t; i < n; i += 256) {
        uint x;
        int y;
        if (i < SCAP) { x = rx[i]; y = (int)ry[i]; }
        else { const int2 r = ebA[lo + i]; x = (uint)r.x; y = r.y; }
        const int sidx = x & 127;
        const uint d = x >> 7;
        const float att = (float)(16384 + y) * fsl[sidx];
        int attq = (int)(att + 0.5f);
        attq = (attq > 32767) ? 32767 : attq;
        const int p = atomicAdd(&cur[sidx], 1);
        ebB[lo + p] = (d << 15) | (uint)attq;
    }
}

// ---------------------------------------------------------------------------
// Aggregation: R8 structure UNCHANGED (proven 95 us / FETCH 87 MB — at the
// L2 random-granule floor: 12.8M touches x 64 B granule = 819 GB @ ~8.6 TB/s).
// slice = blockIdx&7 -> XCD-pinned 3.2 MB hem slice; grid 8*3125 blocks.
// Wave = 8 nodes x 8 feature-pair lanes; 4 B record (broadcast) + 4 B gather.
// ---------------------------------------------------------------------------
__global__ __launch_bounds__(256) void k_aggregate(
    const uint* __restrict__ eb, const int* __restrict__ offs,
    const ushort* __restrict__ hem, float* __restrict__ out0) {
    const int slice = blockIdx.x & 7;
    const int grp = blockIdx.x >> 3;
    const int t = threadIdx.x;
    const int node = grp * 32 + (t >> 3);    // NN = 32*NGRP exactly
    const int f = t & 7;                     // feature-pair within slice
    const uint* hemS = reinterpret_cast<const uint*>(hem)
                     + (size_t)slice * NN * 8 + f;
    const int beg = offs[node];
    const int end = offs[node + 1];

    float a0 = 0.f, a1 = 0.f;
    int j = beg;
    for (; j + 4 <= end; j += 4) {
        const uint r0 = eb[j];
        const uint r1 = eb[j + 1];
        const uint r2 = eb[j + 2];
        const uint r3 = eb[j + 3];
        const float w0 = (float)(r0 & 0x7fffu);
        const float w1 = (float)(r1 & 0x7fffu);
        const float w2 = (float)(r2 & 0x7fffu);
        const float w3 = (float)(r3 & 0x7fffu);
        const uint u0 = hemS[(size_t)(r0 >> 15) * 8];
        const uint u1 = hemS[(size_t)(r1 >> 15) * 8];
        const uint u2 = hemS[(size_t)(r2 >> 15) * 8];
        const uint u3 = hemS[(size_t)(r3 >> 15) * 8];
        a0 += w0 * __uint_as_float(u0 << 16) + w1 * __uint_as_float(u1 << 16)
            + w2 * __uint_as_float(u2 << 16) + w3 * __uint_as_float(u3 << 16);
        a1 += w0 * __uint_as_float(u0 & 0xffff0000u)
            + w1 * __uint_as_float(u1 & 0xffff0000u)
            + w2 * __uint_as_float(u2 & 0xffff0000u)
            + w3 * __uint_as_float(u3 & 0xffff0000u);
    }
    for (; j < end; ++j) {
        const uint r0 = eb[j];
        const float w0 = (float)(r0 & 0x7fffu);
        const uint u0 = hemS[(size_t)(r0 >> 15) * 8];
        a0 += w0 * __uint_as_float(u0 << 16);
        a1 += w0 * __uint_as_float(u0 & 0xffff0000u);
    }
    const float s = 1.f / 32767.f;
    float2 o;
    o.x = a0 * s;
    o.y = a1 * s;
    *reinterpret_cast<float2*>(out0 + (size_t)node * OUTF + slice * 16 + f * 2) = o;
}

// ---------------------------------------------------------------------------
extern "C" void kernel_launch(void* const* d_in, const int* in_sizes, int n_in,
                              void* d_out, int out_size, void* d_ws, size_t ws_size,
                              hipStream_t stream) {
    const float* x   = (const float*)d_in[0];
    const int* eidx  = (const int*)d_in[1];
    const float* W   = (const float*)d_in[2];
    const float* a   = (const float*)d_in[3];
    const float* Wem = (const float*)d_in[4];

    const int* src = eidx;
    const int* dst = eidx + NE;

    float* out0 = (float*)d_out;            // h_prime: NN*128
    float* out1 = out0 + (size_t)NN * OUTF; // edge_e: NE

    // workspace layout (~49 MB), 16B-aligned chunks
    float* wsv   = (float*)d_ws;                     // 256
    float* wdv   = wsv + 256;                        // 256
    float* s1    = wdv + 256;                        // NN
    float* s2    = s1 + NN;                          // NN
    ushort* hem  = (ushort*)(s2 + NN);               // NN*128 bf16 (slice-major)
    ushort* Bsw  = hem + (size_t)NN * OUTF;          // 32768
    int* offs    = (int*)(Bsw + 32768);              // NN+4 (sentinel + pad)
    int* bsumB   = offs + NN + 4;                    // NBK (pad to 784)
    int* bbase   = bsumB + 784;                      // NBK+1 (pad to 788)
    int* cntA    = bbase + 788;                      // NBA*NBK
    int* baseA   = cntA + NBA * NBK;                 // NBA*NBK
    int2* ebA    = (int2*)(baseA + NBA * NBK);       // NE * 8B
    uint* ebB    = (uint*)(ebA + NE);                // NE * 4B

    hipLaunchKernelGGL(k_setup, dim3(9 + NBA), dim3(256), 0, stream,
                       W, a, Wem, src, wsv, wdv, Bsw, cntA);
    hipLaunchKernelGGL(k_mm, dim3((NN + 63) / 64), dim3(256), 0, stream,
                       x, Bsw, wsv, wdv, s1, s2, hem);
    hipLaunchKernelGGL(k_cscan, dim3(NBK), dim3(512), 0, stream, cntA, baseA, bsumB);
    hipLaunchKernelGGL(k_bbase, dim3(1), dim3(1024), 0, stream, bsumB, bbase, offs);
    hipLaunchKernelGGL(k_binA, dim3(NBA), dim3(256), 0, stream,
                       src, dst, s1, s2, out1, bbase, baseA, ebA);
    hipLaunchKernelGGL(k_sortB, dim3(NBK), dim3(256), 0, stream,
                       bbase, ebA, ebB, offs);
    hipLaunchKernelGGL(k_aggregate, dim3(8 * NGRP), dim3(256), 0, stream,
                       ebB, offs, hem, out0);
}

// Round 12
// 156.061 us; speedup vs baseline: 2.0132x; 1.2235x over previous
//
#include <hip/hip_runtime.h>
#include <hip/hip_bf16.h>

#define NN 100000
#define NE 1600000
#define INF 256
#define OUTF 128
#define NBK ((NN + 127) / 128)           // 782 buckets of 128 nodes
#define CHUNK 4096
#define NBA ((NE + CHUNK - 1) / CHUNK)   // 391 chunks
#define NGRP (NN / 32)                   // 3125 (exact)
#define SCAP 6144                        // sortB LDS record cap

typedef __attribute__((ext_vector_type(8))) short short8;
typedef __attribute__((ext_vector_type(4))) float f32x4;

static __device__ __forceinline__ short f2bf(float f) {
    __hip_bfloat16 h = __float2bfloat16(f);
    return *reinterpret_cast<short*>(&h);
}

// ---------------------------------------------------------------------------
// Setup (fused): block 0: wsv = W@a_src, wdv = W@a_dst;
// blocks 1..8: swizzled bf16 B fragments of W_em;
// blocks 9..9+NBA-1: per-chunk per-bucket edge counts.
// ---------------------------------------------------------------------------
__global__ void k_setup(const float* __restrict__ W, const float* __restrict__ a,
                        const float* __restrict__ Wem, const int* __restrict__ src,
                        float* __restrict__ wsv, float* __restrict__ wdv,
                        ushort* __restrict__ Bsw, int* __restrict__ cntA) {
    const int b = blockIdx.x, t = threadIdx.x;
    if (b == 0) {
        const float* Wr = W + (size_t)t * OUTF;
        float sa = 0.f, sb = 0.f;
        #pragma unroll 8
        for (int k = 0; k < OUTF; ++k) {
            float w = Wr[k];
            sa += w * a[k];
            sb += w * a[OUTF + k];
        }
        wsv[t] = sa;
        wdv[t] = sb;
    } else if (b <= 8) {
        const int kt = b - 1;
        for (int idx = t; idx < 4096; idx += 256) {
            const int ct = idx >> 9;
            const int lane = (idx >> 3) & 63;
            const int j = idx & 7;
            const int k = kt * 32 + (lane >> 4) * 8 + j;
            const int c = ct * 16 + (lane & 15);
            Bsw[((size_t)(kt * 8 + ct) * 64 + lane) * 8 + j] =
                (ushort)f2bf(Wem[(size_t)k * OUTF + c]);
        }
    } else {
        __shared__ int cnt[NBK];
        const int c = b - 9;
        const int e0 = c * CHUNK;
        for (int i = t; i < NBK; i += 256) cnt[i] = 0;
        __syncthreads();
        for (int i = t; i < CHUNK; i += 256) {
            const int e = e0 + i;
            if (e < NE) atomicAdd(&cnt[src[e] >> 7], 1);
        }
        __syncthreads();
        for (int i = t; i < NBK; i += 256) cntA[(size_t)c * NBK + i] = cnt[i];
    }
}

// ---------------------------------------------------------------------------
// Fused launch 2: blocks 0..781 = MFMA matmul (128 rows/block, 8 waves);
// blocks 782..1563 = per-bucket scan over chunks (hidden under mm).
// mm: hem8(int8) = round(127 * (x@W_em) / scale[row]), scale[row] = rowmax|.|
//   stored in 4 XCD-L2-resident SLICES of 32-byte rows (3.2 MB each):
//   hem8[(fs*NN + row)*32 + colInSlice],  fs = col>>5.
// Fused f32 s1 = x.ws, s2 = x.wd. C/D map: col = ct*16+(lane&15),
// row = br + (lane>>4)*4 + reg  [m89/m91 verified].
// ---------------------------------------------------------------------------
__global__ __launch_bounds__(512) void k_mmcs(
    const float* __restrict__ x, const ushort* __restrict__ Bsw,
    const float* __restrict__ wsv, const float* __restrict__ wdv,
    const int* __restrict__ cntA,
    float* __restrict__ s1, float* __restrict__ s2,
    char* __restrict__ hem8, float* __restrict__ scaleA,
    int* __restrict__ baseA, int* __restrict__ bsumB) {
    __shared__ int sm[512];
    const int b = blockIdx.x;
    const int t = threadIdx.x;
    if (b < 782) {
        const int w = t >> 6, lane = t & 63;
        const int br = b * 128 + w * 16;
        const int r0 = lane & 15, kq = lane >> 4;
        const int row = br + r0;
        const int rowc = (row < NN) ? row : NN - 1;
        const float* xp = x + (size_t)rowc * INF + kq * 8;
        const short8* bp = reinterpret_cast<const short8*>(Bsw);

        f32x4 acc[8];
        #pragma unroll
        for (int ct = 0; ct < 8; ++ct) acc[ct] = (f32x4){0.f, 0.f, 0.f, 0.f};
        float sa = 0.f, sb = 0.f;

        #pragma unroll
        for (int kt = 0; kt < 8; ++kt) {
            const float4 a0 = *reinterpret_cast<const float4*>(xp + kt * 32);
            const float4 a1 = *reinterpret_cast<const float4*>(xp + kt * 32 + 4);
            const float4 w0 = *reinterpret_cast<const float4*>(wsv + kt * 32 + kq * 8);
            const float4 w1 = *reinterpret_cast<const float4*>(wsv + kt * 32 + kq * 8 + 4);
            const float4 u0 = *reinterpret_cast<const float4*>(wdv + kt * 32 + kq * 8);
            const float4 u1 = *reinterpret_cast<const float4*>(wdv + kt * 32 + kq * 8 + 4);
            sa += a0.x * w0.x + a0.y * w0.y + a0.z * w0.z + a0.w * w0.w
                + a1.x * w1.x + a1.y * w1.y + a1.z * w1.z + a1.w * w1.w;
            sb += a0.x * u0.x + a0.y * u0.y + a0.z * u0.z + a0.w * u0.w
                + a1.x * u1.x + a1.y * u1.y + a1.z * u1.z + a1.w * u1.w;
            short8 af;
            af[0] = f2bf(a0.x); af[1] = f2bf(a0.y); af[2] = f2bf(a0.z); af[3] = f2bf(a0.w);
            af[4] = f2bf(a1.x); af[5] = f2bf(a1.y); af[6] = f2bf(a1.z); af[7] = f2bf(a1.w);
            #pragma unroll
            for (int ct = 0; ct < 8; ++ct) {
                const short8 bf = bp[(size_t)(kt * 8 + ct) * 64 + lane];
                acc[ct] = __builtin_amdgcn_mfma_f32_16x16x32_bf16(af, bf, acc[ct], 0, 0, 0);
            }
        }

        sa += __shfl_xor(sa, 16); sa += __shfl_xor(sa, 32);
        sb += __shfl_xor(sb, 16); sb += __shfl_xor(sb, 32);
        if (kq == 0 && row < NN) { s1[row] = sa; s2[row] = sb; }

        // per-row abs-max over 128 cols (reduce over the 16 r0-lanes)
        float mx[4];
        #pragma unroll
        for (int i = 0; i < 4; ++i) {
            float m = 0.f;
            #pragma unroll
            for (int ct = 0; ct < 8; ++ct) m = fmaxf(m, fabsf(acc[ct][i]));
            m = fmaxf(m, __shfl_xor(m, 1));
            m = fmaxf(m, __shfl_xor(m, 2));
            m = fmaxf(m, __shfl_xor(m, 4));
            m = fmaxf(m, __shfl_xor(m, 8));
            mx[i] = m;
        }
        #pragma unroll
        for (int i = 0; i < 4; ++i) {
            const int rr = br + kq * 4 + i;
            if (rr < NN) {
                if (r0 == 0) scaleA[rr] = mx[i];
                const float inv = (mx[i] > 0.f) ? 127.f / mx[i] : 0.f;
                #pragma unroll
                for (int ct = 0; ct < 8; ++ct) {
                    int q = (int)rintf(acc[ct][i] * inv);
                    q = (q > 127) ? 127 : ((q < -127) ? -127 : q);
                    hem8[((size_t)(ct >> 1) * NN + rr) * 32 + (ct & 1) * 16 + r0] =
                        (char)q;
                }
            }
        }
    } else {
        // cscan: bucket bb, scan NBA=391 chunk counts
        const int bb = b - 782;
        const int v = (t < NBA) ? cntA[(size_t)t * NBK + bb] : 0;
        sm[t] = v;
        __syncthreads();
        for (int off = 1; off < 512; off <<= 1) {
            const int add = (t >= off) ? sm[t - off] : 0;
            __syncthreads();
            sm[t] += add;
            __syncthreads();
        }
        if (t < NBA) baseA[(size_t)t * NBK + bb] = sm[t] - v;
        if (t == 511) bsumB[bb] = sm[511];
    }
}

// ---------------------------------------------------------------------------
// Bucket exclusive scan (1 block, 1024 threads, NBK=782) + sentinels.
// ---------------------------------------------------------------------------
__global__ __launch_bounds__(1024) void k_bbase(
    const int* __restrict__ bsumB, int* __restrict__ bbase,
    int* __restrict__ offs) {
    __shared__ int sm[1024];
    const int t = threadIdx.x;
    const int v = (t < NBK) ? bsumB[t] : 0;
    sm[t] = v;
    __syncthreads();
    for (int off = 1; off < 1024; off <<= 1) {
        const int add = (t >= off) ? sm[t - off] : 0;
        __syncthreads();
        sm[t] += add;
        __syncthreads();
    }
    if (t < NBK) bbase[t] = sm[t] - v;
    if (t == 0) { bbase[NBK] = NE; offs[NN] = NE; }
}

// ---------------------------------------------------------------------------
// Pass A (fused edge_e): single-pass deterministic scatter into bucket runs.
// ebA record: { (dst<<7) | (src&127), vq },  vq = round((exp(sig(ee))-1)*16384)
// ---------------------------------------------------------------------------
__global__ __launch_bounds__(256) void k_binA(
    const int* __restrict__ src, const int* __restrict__ dst,
    const float* __restrict__ s1, const float* __restrict__ s2,
    float* __restrict__ ee_out, const int* __restrict__ bbase,
    const int* __restrict__ baseA, int2* __restrict__ ebA) {
    __shared__ int base[NBK];
    __shared__ int cnt[NBK];
    const int t = threadIdx.x;
    const int c = blockIdx.x;
    const int e0 = c * CHUNK;
    for (int i = t; i < NBK; i += 256) {
        base[i] = bbase[i] + baseA[(size_t)c * NBK + i];
        cnt[i] = 0;
    }
    __syncthreads();
    for (int i = t; i < CHUNK; i += 256) {
        const int e = e0 + i;
        if (e < NE) {
            const int s = src[e], d = dst[e];
            const float ee = s1[s] + s2[d];
            __builtin_nontemporal_store(ee, ee_out + e);
            const float ob = 1.f / (1.f + __expf(-ee));
            const float v = __expf(ob);                   // in (1, e)
            int vq = (int)((v - 1.f) * 16384.f + 0.5f);   // <= 28147
            vq = (vq > 32767) ? 32767 : vq;
            const int bk = s >> 7;
            const int r = atomicAdd(&cnt[bk], 1);
            ebA[base[bk] + r] = make_int2((d << 7) | (s & 127), vq);
        }
    }
}

// ---------------------------------------------------------------------------
// Pass B: one block per bucket, single global read (LDS-staged, SCAP cap
// with global-reread overflow). Pass 1 counts+vq-sums; 128-scan -> CSR offs
// + folded 1/denominator. Pass 2 scatters 4-byte records (dst<<15)|wq with
// the dst's int8 row-scale folded in:
//   att = (16384+vq)/(16384*cnt + vqsum)  in [0,1]
//   wq  = round(att * scaleA[dst] * 1024), clamp 32767  (15 bits)
// Aggregate then computes exact integer dots: acc = sum wq*q,
//   h' = acc / (1024*127).
// ---------------------------------------------------------------------------
__global__ __launch_bounds__(256) void k_sortB(
    const int* __restrict__ bbase, const int2* __restrict__ ebA,
    const float* __restrict__ scaleA,
    uint* __restrict__ ebB, int* __restrict__ offs) {
    __shared__ uint rx[SCAP];
    __shared__ ushort ry[SCAP];
    __shared__ int cnt[128];
    __shared__ int sum[128];
    __shared__ int sm[128];
    __shared__ int cur[128];
    __shared__ float fsl[128];
    const int b = blockIdx.x, t = threadIdx.x;
    const int n0 = b << 7;
    const int lo = bbase[b];
    const int hi = bbase[b + 1];
    const int n = hi - lo;
    if (t < 128) { cnt[t] = 0; sum[t] = 0; }
    __syncthreads();
    for (int i = t; i < n; i += 256) {
        const int2 r = ebA[lo + i];
        if (i < SCAP) { rx[i] = (uint)r.x; ry[i] = (ushort)r.y; }
        const int sidx = r.x & 127;
        atomicAdd(&cnt[sidx], 1);
        atomicAdd(&sum[sidx], r.y);
    }
    __syncthreads();
    const int v = (t < 128) ? cnt[t] : 0;
    if (t < 128) sm[t] = v;
    __syncthreads();
    for (int off = 1; off < 128; off <<= 1) {
        int add = 0;
        if (t < 128 && t >= off) add = sm[t - off];
        __syncthreads();
        if (t < 128) sm[t] += add;
        __syncthreads();
    }
    if (t < 128) {
        const int excl = sm[t] - v;
        cur[t] = excl;
        const int node = n0 + t;
        if (node < NN) offs[node] = lo + excl;
        fsl[t] = (v > 0) ? 1.f / (float)(v * 16384 + sum[t]) : 0.f;
    }
    __syncthreads();
    for (int i = t; i < n; i += 256) {
        uint x;
        int y;
        if (i < SCAP) { x = rx[i]; y = (int)ry[i]; }
        else { const int2 r = ebA[lo + i]; x = (uint)r.x; y = r.y; }
        const int sidx = x & 127;
        const uint d = x >> 7;
        const float att = (float)(16384 + y) * fsl[sidx];
        const float w = att * scaleA[d];
        int wq = (int)(w * 1024.f + 0.5f);
        wq = (wq > 32767) ? 32767 : wq;
        const int p = atomicAdd(&cur[sidx], 1);
        ebB[lo + p] = (d << 15) | (uint)wq;
    }
}

// ---------------------------------------------------------------------------
// Aggregation: int8, 4 slices (HALVES the L2 random-granule touch count:
// 12.8M -> 6.4M touches x 64 B = 410 GB @ ~8.6 TB/s -> ~48 us model floor).
// slice = blockIdx&3 -> XCD-stable (XCD k handles slice k&3 only; tile =
// 3.2 MB resident). Wave = 8 nodes x 8 lanes; lane owns 4 features (1 uint
// of the 32 B int8 row). Inner loop is an EXACT integer dot:
//   acc += wq * q   (wq<=32767, |q|<=127, deg<=~50 -> < 2^31).
// ---------------------------------------------------------------------------
__global__ __launch_bounds__(256) void k_aggregate(
    const uint* __restrict__ eb, const int* __restrict__ offs,
    const char* __restrict__ hem8, float* __restrict__ out0) {
    const int slice = blockIdx.x & 3;
    const int grp = blockIdx.x >> 2;
    const int t = threadIdx.x;
    const int node = grp * 32 + (t >> 3);    // NN = 32*NGRP exactly
    const int f = t & 7;                     // uint (4 features) within slice
    const char* base = hem8 + (size_t)slice * NN * 32 + f * 4;
    const int beg = offs[node];
    const int end = offs[node + 1];

    int a0 = 0, a1 = 0, a2 = 0, a3 = 0;
    int j = beg;
    for (; j + 4 <= end; j += 4) {
        const uint r0 = eb[j];
        const uint r1 = eb[j + 1];
        const uint r2 = eb[j + 2];
        const uint r3 = eb[j + 3];
        const int w0 = (int)(r0 & 0x7fffu);
        const int w1 = (int)(r1 & 0x7fffu);
        const int w2 = (int)(r2 & 0x7fffu);
        const int w3 = (int)(r3 & 0x7fffu);
        const uint u0 = *reinterpret_cast<const uint*>(base + ((size_t)(r0 >> 15)) * 32);
        const uint u1 = *reinterpret_cast<const uint*>(base + ((size_t)(r1 >> 15)) * 32);
        const uint u2 = *reinterpret_cast<const uint*>(base + ((size_t)(r2 >> 15)) * 32);
        const uint u3 = *reinterpret_cast<const uint*>(base + ((size_t)(r3 >> 15)) * 32);
        a0 += w0 * (((int)(u0 << 24)) >> 24) + w1 * (((int)(u1 << 24)) >> 24)
            + w2 * (((int)(u2 << 24)) >> 24) + w3 * (((int)(u3 << 24)) >> 24);
        a1 += w0 * (((int)(u0 << 16)) >> 24) + w1 * (((int)(u1 << 16)) >> 24)
            + w2 * (((int)(u2 << 16)) >> 24) + w3 * (((int)(u3 << 16)) >> 24);
        a2 += w0 * (((int)(u0 << 8)) >> 24) + w1 * (((int)(u1 << 8)) >> 24)
            + w2 * (((int)(u2 << 8)) >> 24) + w3 * (((int)(u3 << 8)) >> 24);
        a3 += w0 * (((int)u0) >> 24) + w1 * (((int)u1) >> 24)
            + w2 * (((int)u2) >> 24) + w3 * (((int)u3) >> 24);
    }
    for (; j < end; ++j) {
        const uint r0 = eb[j];
        const int w0 = (int)(r0 & 0x7fffu);
        const uint u0 = *reinterpret_cast<const uint*>(base + ((size_t)(r0 >> 15)) * 32);
        a0 += w0 * (((int)(u0 << 24)) >> 24);
        a1 += w0 * (((int)(u0 << 16)) >> 24);
        a2 += w0 * (((int)(u0 << 8)) >> 24);
        a3 += w0 * (((int)u0) >> 24);
    }
    const float s = 1.f / (1024.f * 127.f);
    f32x4 o = {a0 * s, a1 * s, a2 * s, a3 * s};
    *reinterpret_cast<f32x4*>(
        out0 + (size_t)node * OUTF + slice * 32 + f * 4) = o;
}

// ---------------------------------------------------------------------------
extern "C" void kernel_launch(void* const* d_in, const int* in_sizes, int n_in,
                              void* d_out, int out_size, void* d_ws, size_t ws_size,
                              hipStream_t stream) {
    const float* x   = (const float*)d_in[0];
    const int* eidx  = (const int*)d_in[1];
    const float* W   = (const float*)d_in[2];
    const float* a   = (const float*)d_in[3];
    const float* Wem = (const float*)d_in[4];

    const int* src = eidx;
    const int* dst = eidx + NE;

    float* out0 = (float*)d_out;            // h_prime: NN*128
    float* out1 = out0 + (size_t)NN * OUTF; // edge_e: NE

    // workspace layout (~37 MB), aligned chunks
    float* wsv    = (float*)d_ws;                    // 256
    float* wdv    = wsv + 256;                       // 256
    float* s1     = wdv + 256;                       // NN
    float* s2     = s1 + NN;                         // NN
    float* scaleA = s2 + NN;                         // NN
    ushort* Bsw   = (ushort*)(scaleA + NN);          // 32768
    int* offs     = (int*)(Bsw + 32768);             // NN+4 (sentinel + pad)
    int* bsumB    = offs + NN + 4;                   // NBK (pad to 784)
    int* bbase    = bsumB + 784;                     // NBK+1 (pad to 788)
    int* cntA     = bbase + 788;                     // NBA*NBK
    int* baseA    = cntA + NBA * NBK;                // NBA*NBK
    int2* ebA     = (int2*)(baseA + NBA * NBK);      // NE * 8B
    uint* ebB     = (uint*)(ebA + NE);               // NE * 4B
    char* hem8    = (char*)(ebB + NE);               // NN*128 int8 (slice-major)

    hipLaunchKernelGGL(k_setup, dim3(9 + NBA), dim3(256), 0, stream,
                       W, a, Wem, src, wsv, wdv, Bsw, cntA);
    hipLaunchKernelGGL(k_mmcs, dim3(782 + 782), dim3(512), 0, stream,
                       x, Bsw, wsv, wdv, cntA, s1, s2, hem8, scaleA,
                       baseA, bsumB);
    hipLaunchKernelGGL(k_bbase, dim3(1), dim3(1024), 0, stream, bsumB, bbase, offs);
    hipLaunchKernelGGL(k_binA, dim3(NBA), dim3(256), 0, stream,
                       src, dst, s1, s2, out1, bbase, baseA, ebA);
    hipLaunchKernelGGL(k_sortB, dim3(NBK), dim3(256), 0, stream,
                       bbase, ebA, scaleA, ebB, offs);
    hipLaunchKernelGGL(k_aggregate, dim3(4 * NGRP), dim3(256), 0, stream,
                       ebB, offs, hem8, out0);
}

// Round 13
// 154.636 us; speedup vs baseline: 2.0318x; 1.0092x over previous
//
#include <hip/hip_runtime.h>
#include <hip/hip_bf16.h>

#define NN 100000
#define NE 1600000
#define INF 256
#define OUTF 128
#define NBK ((NN + 127) / 128)           // 782 buckets of 128 nodes
#define CHUNK 4096
#define NBA ((NE + CHUNK - 1) / CHUNK)   // 391 chunks
#define NGRP (NN / 32)                   // 3125 (exact)
#define SCAP 6144                        // sortB LDS record cap
#define NMM 1563                         // mm blocks (64 rows each)

typedef __attribute__((ext_vector_type(8))) short short8;
typedef __attribute__((ext_vector_type(4))) float f32x4;

static __device__ __forceinline__ short f2bf(float f) {
    __hip_bfloat16 h = __float2bfloat16(f);
    return *reinterpret_cast<short*>(&h);
}

// ---------------------------------------------------------------------------
// Setup (fused): block 0: wsv = W@a_src, wdv = W@a_dst;
// blocks 1..8: swizzled bf16 B fragments of W_em;
// blocks 9..9+NBA-1: per-chunk per-bucket edge counts.
// ---------------------------------------------------------------------------
__global__ void k_setup(const float* __restrict__ W, const float* __restrict__ a,
                        const float* __restrict__ Wem, const int* __restrict__ src,
                        float* __restrict__ wsv, float* __restrict__ wdv,
                        ushort* __restrict__ Bsw, int* __restrict__ cntA) {
    const int b = blockIdx.x, t = threadIdx.x;
    if (b == 0) {
        const float* Wr = W + (size_t)t * OUTF;
        float sa = 0.f, sb = 0.f;
        #pragma unroll 8
        for (int k = 0; k < OUTF; ++k) {
            float w = Wr[k];
            sa += w * a[k];
            sb += w * a[OUTF + k];
        }
        wsv[t] = sa;
        wdv[t] = sb;
    } else if (b <= 8) {
        const int kt = b - 1;
        for (int idx = t; idx < 4096; idx += 256) {
            const int ct = idx >> 9;
            const int lane = (idx >> 3) & 63;
            const int j = idx & 7;
            const int k = kt * 32 + (lane >> 4) * 8 + j;
            const int c = ct * 16 + (lane & 15);
            Bsw[((size_t)(kt * 8 + ct) * 64 + lane) * 8 + j] =
                (ushort)f2bf(Wem[(size_t)k * OUTF + c]);
        }
    } else {
        __shared__ int cnt[NBK];
        const int c = b - 9;
        const int e0 = c * CHUNK;
        for (int i = t; i < NBK; i += 256) cnt[i] = 0;
        __syncthreads();
        for (int i = t; i < CHUNK; i += 256) {
            const int e = e0 + i;
            if (e < NE) atomicAdd(&cnt[src[e] >> 7], 1);
        }
        __syncthreads();
        for (int i = t; i < NBK; i += 256) cntA[(size_t)c * NBK + i] = cnt[i];
    }
}

// ---------------------------------------------------------------------------
// Fused launch 2, 256 threads: blocks 0..NMM-1 = MFMA matmul (64 rows, 4
// waves); blocks NMM..NMM+NBK-1 = per-bucket chunk scan (2 slots/thread).
// mm MLP FIX (R12: VGPR=52 allowed only ~3 x-loads in flight -> 1.1 TB/s):
// all 16 float4 x-loads issue upfront into a register array (~120 VGPR,
// ~16 waves/CU, >=1 MB in flight chip-wide -> ~3 TB/s stream).
// hem8(int8) = round(127 * (x@W_em) / scale[row]); 4 slices of 32 B rows.
// int8 stores packed via 2x shfl_xor into coalesced 4 B word stores.
// ---------------------------------------------------------------------------
__global__ __launch_bounds__(256) void k_mmcs(
    const float* __restrict__ x, const ushort* __restrict__ Bsw,
    const float* __restrict__ wsv, const float* __restrict__ wdv,
    const int* __restrict__ cntA,
    float* __restrict__ s1, float* __restrict__ s2,
    char* __restrict__ hem8, float* __restrict__ scaleA,
    int* __restrict__ baseA, int* __restrict__ bsumB) {
    __shared__ int sm[512];
    const int b = blockIdx.x;
    const int t = threadIdx.x;
    if (b < NMM) {
        const int w = t >> 6, lane = t & 63;
        const int br = b * 64 + w * 16;
        const int r0 = lane & 15, kq = lane >> 4;
        const int row = br + r0;
        const int rowc = (row < NN) ? row : NN - 1;
        const float* xp = x + (size_t)rowc * INF + kq * 8;

        // ---- burst-issue ALL x loads (the MLP fix) ----
        float4 xa[16];
        #pragma unroll
        for (int kt = 0; kt < 8; ++kt) {
            xa[2 * kt]     = *reinterpret_cast<const float4*>(xp + kt * 32);
            xa[2 * kt + 1] = *reinterpret_cast<const float4*>(xp + kt * 32 + 4);
        }

        const short8* bp = reinterpret_cast<const short8*>(Bsw);
        f32x4 acc[8];
        #pragma unroll
        for (int ct = 0; ct < 8; ++ct) acc[ct] = (f32x4){0.f, 0.f, 0.f, 0.f};
        float sa = 0.f, sb = 0.f;

        #pragma unroll
        for (int kt = 0; kt < 8; ++kt) {
            const float4 a0 = xa[2 * kt];
            const float4 a1 = xa[2 * kt + 1];
            const float4 w0 = *reinterpret_cast<const float4*>(wsv + kt * 32 + kq * 8);
            const float4 w1 = *reinterpret_cast<const float4*>(wsv + kt * 32 + kq * 8 + 4);
            const float4 u0 = *reinterpret_cast<const float4*>(wdv + kt * 32 + kq * 8);
            const float4 u1 = *reinterpret_cast<const float4*>(wdv + kt * 32 + kq * 8 + 4);
            sa += a0.x * w0.x + a0.y * w0.y + a0.z * w0.z + a0.w * w0.w
                + a1.x * w1.x + a1.y * w1.y + a1.z * w1.z + a1.w * w1.w;
            sb += a0.x * u0.x + a0.y * u0.y + a0.z * u0.z + a0.w * u0.w
                + a1.x * u1.x + a1.y * u1.y + a1.z * u1.z + a1.w * u1.w;
            short8 af;
            af[0] = f2bf(a0.x); af[1] = f2bf(a0.y); af[2] = f2bf(a0.z); af[3] = f2bf(a0.w);
            af[4] = f2bf(a1.x); af[5] = f2bf(a1.y); af[6] = f2bf(a1.z); af[7] = f2bf(a1.w);
            #pragma unroll
            for (int ct = 0; ct < 8; ++ct) {
                const short8 bf = bp[(size_t)(kt * 8 + ct) * 64 + lane];
                acc[ct] = __builtin_amdgcn_mfma_f32_16x16x32_bf16(af, bf, acc[ct], 0, 0, 0);
            }
        }

        sa += __shfl_xor(sa, 16); sa += __shfl_xor(sa, 32);
        sb += __shfl_xor(sb, 16); sb += __shfl_xor(sb, 32);
        if (kq == 0 && row < NN) { s1[row] = sa; s2[row] = sb; }

        // per-row abs-max over 128 cols (reduce over the 16 r0-lanes)
        float mx[4];
        #pragma unroll
        for (int i = 0; i < 4; ++i) {
            float m = 0.f;
            #pragma unroll
            for (int ct = 0; ct < 8; ++ct) m = fmaxf(m, fabsf(acc[ct][i]));
            m = fmaxf(m, __shfl_xor(m, 1));
            m = fmaxf(m, __shfl_xor(m, 2));
            m = fmaxf(m, __shfl_xor(m, 4));
            m = fmaxf(m, __shfl_xor(m, 8));
            mx[i] = m;
        }
        #pragma unroll
        for (int i = 0; i < 4; ++i) {
            const int rr = br + kq * 4 + i;
            const float inv = (mx[i] > 0.f) ? 127.f / mx[i] : 0.f;
            if (r0 == 0 && rr < NN) scaleA[rr] = mx[i];
            #pragma unroll
            for (int ct = 0; ct < 8; ++ct) {
                int q = (int)rintf(acc[ct][i] * inv);
                q = (q > 127) ? 127 : ((q < -127) ? -127 : q);
                // pack 4 consecutive-r0 bytes into one word (2x shfl_xor)
                uint p = (uint)(q & 255);
                p |= ((uint)__shfl_xor((int)p, 1) & 255u) << 8;
                uint word = p | ((uint)__shfl_xor((int)p, 2) << 16);
                if ((r0 & 3) == 0 && rr < NN) {
                    *reinterpret_cast<uint*>(
                        hem8 + ((size_t)(ct >> 1) * NN + rr) * 32
                             + (ct & 1) * 16 + r0) = word;
                }
            }
        }
    } else {
        // cscan: bucket bb; 256 threads scan 512 slots (2 per thread)
        const int bb = b - NMM;
        const int v0 = (t < NBA) ? cntA[(size_t)t * NBK + bb] : 0;
        const int t2 = t + 256;
        const int v1 = (t2 < NBA) ? cntA[(size_t)t2 * NBK + bb] : 0;
        sm[t] = v0;
        sm[t2] = v1;
        __syncthreads();
        for (int off = 1; off < 512; off <<= 1) {
            const int a0 = (t >= off) ? sm[t - off] : 0;
            const int a1 = (t2 >= off) ? sm[t2 - off] : 0;
            __syncthreads();
            sm[t] += a0;
            sm[t2] += a1;
            __syncthreads();
        }
        if (t < NBA) baseA[(size_t)t * NBK + bb] = sm[t] - v0;
        if (t2 < NBA) baseA[(size_t)t2 * NBK + bb] = sm[t2] - v1;
        if (t == 255) bsumB[bb] = sm[511];
    }
}

// ---------------------------------------------------------------------------
// Bucket exclusive scan (1 block, 1024 threads, NBK=782) + sentinels.
// ---------------------------------------------------------------------------
__global__ __launch_bounds__(1024) void k_bbase(
    const int* __restrict__ bsumB, int* __restrict__ bbase,
    int* __restrict__ offs) {
    __shared__ int sm[1024];
    const int t = threadIdx.x;
    const int v = (t < NBK) ? bsumB[t] : 0;
    sm[t] = v;
    __syncthreads();
    for (int off = 1; off < 1024; off <<= 1) {
        const int add = (t >= off) ? sm[t - off] : 0;
        __syncthreads();
        sm[t] += add;
        __syncthreads();
    }
    if (t < NBK) bbase[t] = sm[t] - v;
    if (t == 0) { bbase[NBK] = NE; offs[NN] = NE; }
}

// ---------------------------------------------------------------------------
// Pass A (fused edge_e): single-pass deterministic scatter into bucket runs.
// ebA record: { (dst<<7) | (src&127), vq },  vq = round((exp(sig(ee))-1)*16384)
// ---------------------------------------------------------------------------
__global__ __launch_bounds__(256) void k_binA(
    const int* __restrict__ src, const int* __restrict__ dst,
    const float* __restrict__ s1, const float* __restrict__ s2,
    float* __restrict__ ee_out, const int* __restrict__ bbase,
    const int* __restrict__ baseA, int2* __restrict__ ebA) {
    __shared__ int base[NBK];
    __shared__ int cnt[NBK];
    const int t = threadIdx.x;
    const int c = blockIdx.x;
    const int e0 = c * CHUNK;
    for (int i = t; i < NBK; i += 256) {
        base[i] = bbase[i] + baseA[(size_t)c * NBK + i];
        cnt[i] = 0;
    }
    __syncthreads();
    for (int i = t; i < CHUNK; i += 256) {
        const int e = e0 + i;
        if (e < NE) {
            const int s = src[e], d = dst[e];
            const float ee = s1[s] + s2[d];
            __builtin_nontemporal_store(ee, ee_out + e);
            const float ob = 1.f / (1.f + __expf(-ee));
            const float v = __expf(ob);                   // in (1, e)
            int vq = (int)((v - 1.f) * 16384.f + 0.5f);   // <= 28147
            vq = (vq > 32767) ? 32767 : vq;
            const int bk = s >> 7;
            const int r = atomicAdd(&cnt[bk], 1);
            ebA[base[bk] + r] = make_int2((d << 7) | (s & 127), vq);
        }
    }
}

// ---------------------------------------------------------------------------
// Pass B: one block per bucket, single global read (LDS-staged, SCAP cap
// with global-reread overflow). Pass 1 counts+vq-sums; 128-scan -> CSR offs
// + folded 1/denominator. Pass 2 scatters 4-byte records (dst<<15)|wq with
// the dst's int8 row-scale folded in:
//   att = (16384+vq)/(16384*cnt + vqsum)  in [0,1]
//   wq  = round(att * scaleA[dst] * 1024), clamp 32767  (15 bits)
// ---------------------------------------------------------------------------
__global__ __launch_bounds__(256) void k_sortB(
    const int* __restrict__ bbase, const int2* __restrict__ ebA,
    const float* __restrict__ scaleA,
    uint* __restrict__ ebB, int* __restrict__ offs) {
    __shared__ uint rx[SCAP];
    __shared__ ushort ry[SCAP];
    __shared__ int cnt[128];
    __shared__ int sum[128];
    __shared__ int sm[128];
    __shared__ int cur[128];
    __shared__ float fsl[128];
    const int b = blockIdx.x, t = threadIdx.x;
    const int n0 = b << 7;
    const int lo = bbase[b];
    const int hi = bbase[b + 1];
    const int n = hi - lo;
    if (t < 128) { cnt[t] = 0; sum[t] = 0; }
    __syncthreads();
    for (int i = t; i < n; i += 256) {
        const int2 r = ebA[lo + i];
        if (i < SCAP) { rx[i] = (uint)r.x; ry[i] = (ushort)r.y; }
        const int sidx = r.x & 127;
        atomicAdd(&cnt[sidx], 1);
        atomicAdd(&sum[sidx], r.y);
    }
    __syncthreads();
    const int v = (t < 128) ? cnt[t] : 0;
    if (t < 128) sm[t] = v;
    __syncthreads();
    for (int off = 1; off < 128; off <<= 1) {
        int add = 0;
        if (t < 128 && t >= off) add = sm[t - off];
        __syncthreads();
        if (t < 128) sm[t] += add;
        __syncthreads();
    }
    if (t < 128) {
        const int excl = sm[t] - v;
        cur[t] = excl;
        const int node = n0 + t;
        if (node < NN) offs[node] = lo + excl;
        fsl[t] = (v > 0) ? 1.f / (float)(v * 16384 + sum[t]) : 0.f;
    }
    __syncthreads();
    for (int i = t; i < n; i += 256) {
        uint x;
        int y;
        if (i < SCAP) { x = rx[i]; y = (int)ry[i]; }
        else { const int2 r = ebA[lo + i]; x = (uint)r.x; y = r.y; }
        const int sidx = x & 127;
        const uint d = x >> 7;
        const float att = (float)(16384 + y) * fsl[sidx];
        const float w = att * scaleA[d];
        int wq = (int)(w * 1024.f + 0.5f);
        wq = (wq > 32767) ? 32767 : wq;
        const int p = atomicAdd(&cur[sidx], 1);
        ebB[lo + p] = (d << 15) | (uint)wq;
    }
}

// ---------------------------------------------------------------------------
// Aggregation: int8, 4 slices (6.4M touches x 64 B = 410 GB @ ~8.6 TB/s).
// slice = blockIdx&3 -> XCD-stable; tile = 3.2 MB resident. Wave = 8 nodes
// x 8 lanes; lane owns 4 features (1 uint of the 32 B int8 row). Inner loop
// is an exact integer dot: acc += wq * q.
// ---------------------------------------------------------------------------
__global__ __launch_bounds__(256) void k_aggregate(
    const uint* __restrict__ eb, const int* __restrict__ offs,
    const char* __restrict__ hem8, float* __restrict__ out0) {
    const int slice = blockIdx.x & 3;
    const int grp = blockIdx.x >> 2;
    const int t = threadIdx.x;
    const int node = grp * 32 + (t >> 3);    // NN = 32*NGRP exactly
    const int f = t & 7;                     // uint (4 features) within slice
    const char* base = hem8 + (size_t)slice * NN * 32 + f * 4;
    const int beg = offs[node];
    const int end = offs[node + 1];

    int a0 = 0, a1 = 0, a2 = 0, a3 = 0;
    int j = beg;
    for (; j + 4 <= end; j += 4) {
        const uint r0 = eb[j];
        const uint r1 = eb[j + 1];
        const uint r2 = eb[j + 2];
        const uint r3 = eb[j + 3];
        const int w0 = (int)(r0 & 0x7fffu);
        const int w1 = (int)(r1 & 0x7fffu);
        const int w2 = (int)(r2 & 0x7fffu);
        const int w3 = (int)(r3 & 0x7fffu);
        const uint u0 = *reinterpret_cast<const uint*>(base + ((size_t)(r0 >> 15)) * 32);
        const uint u1 = *reinterpret_cast<const uint*>(base + ((size_t)(r1 >> 15)) * 32);
        const uint u2 = *reinterpret_cast<const uint*>(base + ((size_t)(r2 >> 15)) * 32);
        const uint u3 = *reinterpret_cast<const uint*>(base + ((size_t)(r3 >> 15)) * 32);
        a0 += w0 * (((int)(u0 << 24)) >> 24) + w1 * (((int)(u1 << 24)) >> 24)
            + w2 * (((int)(u2 << 24)) >> 24) + w3 * (((int)(u3 << 24)) >> 24);
        a1 += w0 * (((int)(u0 << 16)) >> 24) + w1 * (((int)(u1 << 16)) >> 24)
            + w2 * (((int)(u2 << 16)) >> 24) + w3 * (((int)(u3 << 16)) >> 24);
        a2 += w0 * (((int)(u0 << 8)) >> 24) + w1 * (((int)(u1 << 8)) >> 24)
            + w2 * (((int)(u2 << 8)) >> 24) + w3 * (((int)(u3 << 8)) >> 24);
        a3 += w0 * (((int)u0) >> 24) + w1 * (((int)u1) >> 24)
            + w2 * (((int)u2) >> 24) + w3 * (((int)u3) >> 24);
    }
    for (; j < end; ++j) {
        const uint r0 = eb[j];
        const int w0 = (int)(r0 & 0x7fffu);
        const uint u0 = *reinterpret_cast<const uint*>(base + ((size_t)(r0 >> 15)) * 32);
        a0 += w0 * (((int)(u0 << 24)) >> 24);
        a1 += w0 * (((int)(u0 << 16)) >> 24);
        a2 += w0 * (((int)(u0 << 8)) >> 24);
        a3 += w0 * (((int)u0) >> 24);
    }
    const float s = 1.f / (1024.f * 127.f);
    f32x4 o = {a0 * s, a1 * s, a2 * s, a3 * s};
    *reinterpret_cast<f32x4*>(
        out0 + (size_t)node * OUTF + slice * 32 + f * 4) = o;
}

// ---------------------------------------------------------------------------
extern "C" void kernel_launch(void* const* d_in, const int* in_sizes, int n_in,
                              void* d_out, int out_size, void* d_ws, size_t ws_size,
                              hipStream_t stream) {
    const float* x   = (const float*)d_in[0];
    const int* eidx  = (const int*)d_in[1];
    const float* W   = (const float*)d_in[2];
    const float* a   = (const float*)d_in[3];
    const float* Wem = (const float*)d_in[4];

    const int* src = eidx;
    const int* dst = eidx + NE;

    float* out0 = (float*)d_out;            // h_prime: NN*128
    float* out1 = out0 + (size_t)NN * OUTF; // edge_e: NE

    // workspace layout (~37 MB), aligned chunks
    float* wsv    = (float*)d_ws;                    // 256
    float* wdv    = wsv + 256;                       // 256
    float* s1     = wdv + 256;                       // NN
    float* s2     = s1 + NN;                         // NN
    float* scaleA = s2 + NN;                         // NN
    ushort* Bsw   = (ushort*)(scaleA + NN);          // 32768
    int* offs     = (int*)(Bsw + 32768);             // NN+4 (sentinel + pad)
    int* bsumB    = offs + NN + 4;                   // NBK (pad to 784)
    int* bbase    = bsumB + 784;                     // NBK+1 (pad to 788)
    int* cntA     = bbase + 788;                     // NBA*NBK
    int* baseA    = cntA + NBA * NBK;                // NBA*NBK
    int2* ebA     = (int2*)(baseA + NBA * NBK);      // NE * 8B
    uint* ebB     = (uint*)(ebA + NE);               // NE * 4B
    char* hem8    = (char*)(ebB + NE);               // NN*128 int8 (slice-major)

    hipLaunchKernelGGL(k_setup, dim3(9 + NBA), dim3(256), 0, stream,
                       W, a, Wem, src, wsv, wdv, Bsw, cntA);
    hipLaunchKernelGGL(k_mmcs, dim3(NMM + NBK), dim3(256), 0, stream,
                       x, Bsw, wsv, wdv, cntA, s1, s2, hem8, scaleA,
                       baseA, bsumB);
    hipLaunchKernelGGL(k_bbase, dim3(1), dim3(1024), 0, stream, bsumB, bbase, offs);
    hipLaunchKernelGGL(k_binA, dim3(NBA), dim3(256), 0, stream,
                       src, dst, s1, s2, out1, bbase, baseA, ebA);
    hipLaunchKernelGGL(k_sortB, dim3(NBK), dim3(256), 0, stream,
                       bbase, ebA, scaleA, ebB, offs);
    hipLaunchKernelGGL(k_aggregate, dim3(4 * NGRP), dim3(256), 0, stream,
                       ebB, offs, hem8, out0);
}